// Round 6
// baseline (2030.516 us; speedup 1.0000x reference)
//
#include <hip/hip_runtime.h>
#include <hip/hip_bf16.h>

// Problem constants
#define TT 16
#define MM 1024
#define HDIM 128
#define NHEADS 4
#define NROWS (TT*MM)          // 16384
#define MAXDEG 64

// ---------------- mask + neighbor-list build ----------------
__global__ __launch_bounds__(256) void k_init(const int* __restrict__ ego,
                                              float* __restrict__ mfl,
                                              int* __restrict__ cnt) {
    int idx = blockIdx.x * 256 + threadIdx.x;   // < 16384
    int t = idx >> 10, i = idx & 1023;
    int b = i >> 8, n = i & 255;
    mfl[idx] = ego[b * (TT * 256) + t * 256 + n] ? 1.f : 0.f;
    cnt[idx] = 0;
}

__global__ __launch_bounds__(256) void k_edges(const float* __restrict__ adj,
                                               const float* __restrict__ mfl,
                                               int* __restrict__ cnt,
                                               int* __restrict__ nbr) {
    int bid = blockIdx.x;            // 256 blocks: t(16) x jc(4) x ic(4)
    int t = bid >> 4, jc = (bid >> 2) & 3, ic = bid & 3;
    int tid = threadIdx.x;
    int i = ic * 256 + tid;
    int row = t * MM + i;
    __shared__ float ms[256];
    int j0 = jc * 256;
    ms[tid] = mfl[t * MM + j0 + tid];
    __syncthreads();
    float mi = mfl[row];
    if (mi == 0.f) return;
    const float* at = adj + (size_t)t * MM * MM;
    for (int jj = 0; jj < 256; ++jj) {
        int j = j0 + jj;
        bool e;
        if (j == i) e = true;                                   // self-loop
        else e = (at[(size_t)j * MM + i] != 0.f) && (ms[jj] != 0.f);
        if (e) {
            int pos = atomicAdd(&cnt[row], 1);
            if (pos < MAXDEG) nbr[(size_t)row * MAXDEG + pos] = j;
        }
    }
}

// ---------------- GAT layer 1: projection (F=2) + fused ss/sd ----------------
__global__ __launch_bounds__(128) void k_gat1(const float* __restrict__ x,
                                              const float* __restrict__ W,
                                              const float* __restrict__ asrc,
                                              const float* __restrict__ adst,
                                              float* __restrict__ h,
                                              float* __restrict__ ss,
                                              float* __restrict__ sd) {
    int bid = blockIdx.x;
    int row = ((bid & 7) << 11) + (bid >> 3);   // XCD-locality swizzle
    int tid = threadIdx.x;
    float x0 = x[row * 2], x1 = x[row * 2 + 1];
    float s4[4], d4[4];
#pragma unroll
    for (int hh = 0; hh < 4; ++hh) {
        int o = hh * 128 + tid;
        float v = x0 * W[o] + x1 * W[512 + o];
        h[(size_t)row * 512 + o] = v;
        s4[hh] = v * asrc[o];
        d4[hh] = v * adst[o];
    }
#pragma unroll
    for (int hh = 0; hh < 4; ++hh)
        for (int off = 32; off; off >>= 1) {
            s4[hh] += __shfl_down(s4[hh], off, 64);
            d4[hh] += __shfl_down(d4[hh], off, 64);
        }
    __shared__ float red[2][2][4];
    if ((tid & 63) == 0) {
        int w = tid >> 6;
#pragma unroll
        for (int hh = 0; hh < 4; ++hh) { red[w][0][hh] = s4[hh]; red[w][1][hh] = d4[hh]; }
    }
    __syncthreads();
    if (tid < 4) ss[row * 4 + tid] = red[0][0][tid] + red[1][0][tid];
    else if (tid < 8) sd[row * 4 + tid - 4] = red[0][1][tid - 4] + red[1][1][tid - 4];
}

// ---------------- GEMM with acc export (for k_gat_h): [16,K]@[K,OTILE*128] ----------------
template <int K, int OTILE, int WKS, int WOS, int ORS, int OOS>
__device__ __forceinline__ void gemm16e(const float* __restrict__ Xs,
                                        const float* __restrict__ W,
                                        float* __restrict__ Out,
                                        float (&acc)[8][OTILE]) {
    const int tid = threadIdx.x;
    const int og = tid & 127;
    const int r0 = (tid >> 7) * 8;
#pragma unroll
    for (int r = 0; r < 8; ++r)
#pragma unroll
        for (int ot = 0; ot < OTILE; ++ot) acc[r][ot] = 0.f;
    for (int k = 0; k < K; k += 4) {
        float4 xv[8];
#pragma unroll
        for (int r = 0; r < 8; ++r)
            xv[r] = *(const float4*)(Xs + (r0 + r) * K + k);
#pragma unroll
        for (int ot = 0; ot < OTILE; ++ot) {
            const float* wp = W + ot * WOS + og;
            float w0 = wp[(k + 0) * WKS];
            float w1 = wp[(k + 1) * WKS];
            float w2 = wp[(k + 2) * WKS];
            float w3 = wp[(k + 3) * WKS];
#pragma unroll
            for (int r = 0; r < 8; ++r)
                acc[r][ot] += xv[r].x * w0 + xv[r].y * w1 + xv[r].z * w2 + xv[r].w * w3;
        }
    }
#pragma unroll
    for (int ot = 0; ot < OTILE; ++ot)
#pragma unroll
        for (int r = 0; r < 8; ++r)
            Out[(r0 + r) * ORS + ot * OOS + og] = acc[r][ot];
}

// ---------------- GAT layers 2-6: projection (F=128) + fused ss/sd ----------------
__global__ __launch_bounds__(256, 4) void k_gat_h(const float* __restrict__ x,
                                                  const float* __restrict__ W,
                                                  const float* __restrict__ asrc,
                                                  const float* __restrict__ adst,
                                                  float* __restrict__ h,
                                                  float* __restrict__ ss,
                                                  float* __restrict__ sd) {
    __shared__ __align__(16) float Xs[2048];
    __shared__ float sred[4][8][4], dred[4][8][4];
    int bid = blockIdx.x;
    int row0 = (((bid & 7) << 7) + (bid >> 3)) * 16;   // band swizzle, same XCD mapping
    int tid = threadIdx.x;
    for (int idx = tid; idx < 2048; idx += 256)
        Xs[idx] = x[(size_t)row0 * 128 + idx];
    __syncthreads();
    float acc[8][4];
    gemm16e<128, 4, 512, 128, 512, 128>(Xs, W, h + (size_t)row0 * 512, acc);
    int og = tid & 127, wave = tid >> 6;
#pragma unroll
    for (int r = 0; r < 8; ++r) {
#pragma unroll
        for (int ot = 0; ot < 4; ++ot) {
            float s = acc[r][ot] * asrc[ot * 128 + og];
            float d = acc[r][ot] * adst[ot * 128 + og];
#pragma unroll
            for (int off = 32; off; off >>= 1) {
                s += __shfl_xor(s, off, 64);
                d += __shfl_xor(d, off, 64);
            }
            if ((tid & 63) == 0) { sred[wave][r][ot] = s; dred[wave][r][ot] = d; }
        }
    }
    __syncthreads();
    if (tid < 64) {
        int r = tid >> 2, hh = tid & 3;
        int w0 = (r >> 3) * 2, rr = r & 7;
        ss[(row0 + r) * 4 + hh] = sred[w0][rr][hh] + sred[w0 + 1][rr][hh];
        sd[(row0 + r) * 4 + hh] = dred[w0][rr][hh] + dred[w0 + 1][rr][hh];
    }
}

// ---------------- GAT aggregation (segment softmax + gather), XCD-swizzled ----------------
__global__ __launch_bounds__(128) void k_agg(const float* __restrict__ h,
                                             const float* __restrict__ ss,
                                             const float* __restrict__ sd,
                                             const int* __restrict__ cnt,
                                             const int* __restrict__ nbr,
                                             const float* __restrict__ mfl,
                                             const float* __restrict__ bias,
                                             float* __restrict__ xo) {
    int bid = blockIdx.x;
    int row = ((bid & 7) << 11) + (bid >> 3);   // same-t rows colocate per XCD
    int tid = threadIdx.x;
    int t = row >> 10;
    if (mfl[row] == 0.f) { xo[(size_t)row * 128 + tid] = 0.f; return; }
    int c = cnt[row]; if (c > MAXDEG) c = MAXDEG;
    __shared__ int nb[MAXDEG];
    __shared__ float al[MAXDEG][4];
    if (tid < c) nb[tid] = nbr[(size_t)row * MAXDEG + tid];
    __syncthreads();
    for (int idx = tid; idx < c * 4; idx += 128) {
        int n = idx >> 2, hh = idx & 3, j = nb[n];
        float lg = sd[row * 4 + hh] + ss[(t * MM + j) * 4 + hh];
        al[n][hh] = lg > 0.f ? lg : 0.2f * lg;   // leaky_relu 0.2
    }
    __syncthreads();
    if (tid < 4) {
        float mx = -1e30f;
        for (int n = 0; n < c; ++n) mx = fmaxf(mx, al[n][tid]);
        float s = 0.f;
        for (int n = 0; n < c; ++n) { float e = __expf(al[n][tid] - mx); al[n][tid] = e; s += e; }
        float inv = 1.f / s;
        for (int n = 0; n < c; ++n) al[n][tid] *= inv;
    }
    __syncthreads();
    float a0 = 0, a1 = 0, a2 = 0, a3 = 0;
    for (int n = 0; n < c; ++n) {
        int j = nb[n];
        const float* hp = h + ((size_t)(t * MM + j)) * 512 + tid;
        a0 += al[n][0] * hp[0];
        a1 += al[n][1] * hp[128];
        a2 += al[n][2] * hp[256];
        a3 += al[n][3] * hp[384];
    }
    float v = 0.25f * (a0 + a1 + a2 + a3) + bias[tid];
    xo[(size_t)row * 128 + tid] = fmaxf(v, 0.f);
}

// ---------------- generic GEMM for k_tf: [16,K]@[K,OG*OTILE], scalar weight loads ----------
// og = tid % OG; r0 = (tid/OG)*RT.  W addr: W + ot*WOS + k*WK + og.
// Out: Out + row*OSTR + ot*OOS + og.  LDS bytes/FMA = 4/OTILE * (RT rows amortized).
template <int K, int XSTR, int OG, int OTILE, int WK, int WOS, int OSTR, int OOS, int BOS>
__device__ __forceinline__ void gemmT(const float* __restrict__ Xs,
                                      const float* __restrict__ W,
                                      const float* __restrict__ bias,
                                      float* __restrict__ Out,
                                      bool accum, bool relu) {
    constexpr int RG = 256 / OG;
    constexpr int RT = 16 / RG;
    const int tid = threadIdx.x;
    const int og = tid % OG;
    const int r0 = (tid / OG) * RT;
    float acc[RT][OTILE];
#pragma unroll
    for (int r = 0; r < RT; ++r)
#pragma unroll
        for (int ot = 0; ot < OTILE; ++ot) acc[r][ot] = 0.f;
    for (int k = 0; k < K; k += 4) {
        float4 xv[RT];
#pragma unroll
        for (int r = 0; r < RT; ++r)
            xv[r] = *(const float4*)(Xs + (r0 + r) * XSTR + k);
#pragma unroll
        for (int ot = 0; ot < OTILE; ++ot) {
            const float* wp = W + ot * WOS + og;
            float w0 = wp[(k + 0) * WK];
            float w1 = wp[(k + 1) * WK];
            float w2 = wp[(k + 2) * WK];
            float w3 = wp[(k + 3) * WK];
#pragma unroll
            for (int r = 0; r < RT; ++r)
                acc[r][ot] += xv[r].x * w0 + xv[r].y * w1 + xv[r].z * w2 + xv[r].w * w3;
        }
    }
#pragma unroll
    for (int ot = 0; ot < OTILE; ++ot) {
        float bb = bias ? bias[ot * BOS + og] : 0.f;
#pragma unroll
        for (int r = 0; r < RT; ++r) {
            float v = acc[r][ot] + bb;
            if (relu) v = fmaxf(v, 0.f);
            float* op = Out + (r0 + r) * OSTR + ot * OOS + og;
            if (accum) *op += v; else *op = v;
        }
    }
}

// ---------------- in-place LayerNorm, 16 rows x 128, 256 threads ----------------
__device__ __forceinline__ void ln256(float* xs, const float* s, const float* b) {
    int tid = threadIdx.x, row = tid >> 4, lane = tid & 15;
    float* xr = xs + row * 128;
    float sum = 0.f;
#pragma unroll
    for (int k2 = 0; k2 < 8; ++k2) sum += xr[lane + 16 * k2];
#pragma unroll
    for (int off = 8; off; off >>= 1) sum += __shfl_xor(sum, off, 16);
    float mean = sum * (1.f / 128.f);
    float vs = 0.f;
#pragma unroll
    for (int k2 = 0; k2 < 8; ++k2) { float d = xr[lane + 16 * k2] - mean; vs += d * d; }
#pragma unroll
    for (int off = 8; off; off >>= 1) vs += __shfl_xor(vs, off, 16);
    float rstd = rsqrtf(vs * (1.f / 128.f) + 1e-5f);
#pragma unroll
    for (int k2 = 0; k2 < 8; ++k2) {
        int d = lane + 16 * k2;
        float v = (xr[d] - mean) * rstd;
        xr[d] = v * s[d] + b[d];
    }
    __syncthreads();
}

// ---------------- 5-layer transformer, 1 seq per 256-thread block ----------------
// LDS = 2048(xs) + 3*2112(Q,K,V) + 1024(scores) = 9408 fl = 37632 B -> 4 blocks/CU.
// FF hidden chunk (16 x 260) overlays the dead Q+K regions.
__global__ __launch_bounds__(256, 4) void k_tf(const float* __restrict__ xg,
        const float* __restrict__ Wqkv, const float* __restrict__ bqkv,
        const float* __restrict__ Wo,   const float* __restrict__ bo,
        const float* __restrict__ ln1s, const float* __restrict__ ln1b,
        const float* __restrict__ ln2s, const float* __restrict__ ln2b,
        const float* __restrict__ Wff1, const float* __restrict__ bff1,
        const float* __restrict__ Wff2, const float* __restrict__ bff2,
        float* __restrict__ out) {
    __shared__ __align__(16) float smem[9408];
    float* xs  = smem;            // 2048: residual, stride 128
    float* Qb  = smem + 2048;     // 2112: Q (stride 132); attn-out O; hid overlay
    float* Kb  = smem + 4160;     // 2112: K (stride 132); hid overlay tail
    float* Vb  = smem + 6272;     // 2112: V (stride 132); FF2 accumulator
    float* sb  = smem + 8384;     // 1024: scores transposed [tk][hh*16+tq]
    float* hid = smem + 2048;     // 4160: FF1 chunk, 16 x 260 (overlays Q+K)
    int m = blockIdx.x, tid = threadIdx.x;

    // load + sinusoidal PE
    for (int idx = tid; idx < 2048; idx += 256) {
        int t = idx >> 7, d = idx & 127, jj = d >> 1;
        float arg = (float)t * expf(-(float)(2 * jj) * (9.210340371976184f / 128.f));
        float pe = (d & 1) ? cosf(arg) : sinf(arg);
        xs[idx] = xg[(size_t)t * (MM * HDIM) + (size_t)m * HDIM + d] + pe;
    }
    __syncthreads();

    for (int l = 0; l < 5; ++l) {
        // ---- QKV: OG=64, OTILE=6 (3 mats x 2 col-halves), 0.67 B/FMA ----
        {
            const int og = tid & 63, r0 = (tid >> 6) * 4;
            float acc[4][6];
#pragma unroll
            for (int r = 0; r < 4; ++r)
#pragma unroll
                for (int u = 0; u < 6; ++u) acc[r][u] = 0.f;
            const float* Wl = Wqkv + (size_t)l * 49152;
            for (int k = 0; k < 128; k += 4) {
                float4 xv[4];
#pragma unroll
                for (int r = 0; r < 4; ++r)
                    xv[r] = *(const float4*)(xs + (r0 + r) * 128 + k);
#pragma unroll
                for (int kk = 0; kk < 4; ++kk) {
#pragma unroll
                    for (int u = 0; u < 6; ++u) {
                        int mt = u >> 1, cc = u & 1;
                        float w = Wl[mt * 16384 + (k + kk) * 128 + cc * 64 + og];
#pragma unroll
                        for (int r = 0; r < 4; ++r)
                            acc[r][u] += ((const float*)&xv[r])[kk] * w;
                    }
                }
            }
#pragma unroll
            for (int u = 0; u < 6; ++u) {
                int mt = u >> 1, cc = u & 1;
                float bb = bqkv[l * 384 + mt * 128 + cc * 64 + og];
                float* ob = (mt == 0) ? Qb : (mt == 1) ? Kb : Vb;
#pragma unroll
                for (int r = 0; r < 4; ++r)
                    ob[(r0 + r) * 132 + cc * 64 + og] = acc[r][u] + bb;
            }
        }
        __syncthreads();
        // ---- scores: thread = (hh, tq, tk0..tk0+3); write transposed sb[tk][hh*16+tq] ----
        {
            int hh = tid >> 6, tq = (tid >> 2) & 15, tk0 = (tid & 3) * 4;
            const float* qp = Qb + tq * 132 + hh * 32;
            float a[4] = {0.f, 0.f, 0.f, 0.f};
#pragma unroll
            for (int d = 0; d < 8; ++d) {
                float4 q4 = *(const float4*)(qp + 4 * d);
#pragma unroll
                for (int j = 0; j < 4; ++j) {
                    float4 k4 = *(const float4*)(Kb + (tk0 + j) * 132 + hh * 32 + 4 * d);
                    a[j] += q4.x * k4.x + q4.y * k4.y + q4.z * k4.z + q4.w * k4.w;
                }
            }
#pragma unroll
            for (int j = 0; j < 4; ++j)
                sb[(tk0 + j) * 64 + hh * 16 + tq] = a[j] * 0.17677669529663687f;
        }
        __syncthreads();
        if (tid < 64) {   // softmax per (hh,tq) column
            float mx = -1e30f;
#pragma unroll
            for (int u = 0; u < 16; ++u) mx = fmaxf(mx, sb[u * 64 + tid]);
            float s = 0.f;
#pragma unroll
            for (int u = 0; u < 16; ++u) { float e = __expf(sb[u * 64 + tid] - mx); sb[u * 64 + tid] = e; s += e; }
            float inv = 1.f / s;
#pragma unroll
            for (int u = 0; u < 16; ++u) sb[u * 64 + tid] *= inv;
        }
        __syncthreads();
        // ---- O = P @ V -> Qb (Q fully consumed before softmax barrier) ----
        {
            int o = tid & 127, r0p = (tid >> 7) * 8, hh = o >> 5;
            float accp[8] = {0, 0, 0, 0, 0, 0, 0, 0};
            for (int u = 0; u < 16; ++u) {
                float vv = Vb[u * 132 + o];
                const float* pp = sb + u * 64 + hh * 16 + r0p;
#pragma unroll
                for (int r = 0; r < 8; ++r) accp[r] += pp[r] * vv;
            }
#pragma unroll
            for (int r = 0; r < 8; ++r) Qb[(r0p + r) * 132 + o] = accp[r];
        }
        __syncthreads();
        // ---- Wo (OG=32, OTILE=4, 1 B/FMA): accumulate into residual xs ----
        gemmT<128, 132, 32, 4, 128, 32, 128, 32, 32>(
            Qb, Wo + (size_t)l * 16384, bo + l * 128, xs, true, false);
        __syncthreads();
        ln256(xs, ln1s + l * 128, ln1b + l * 128);
        // ---- FF: 2 chunks of 256 hidden; hid overlays Q+K; FF2 accumulates into Vb ----
        for (int ch = 0; ch < 2; ++ch) {
            gemmT<128, 128, 64, 4, 512, 64, 260, 64, 64>(
                xs, Wff1 + (size_t)l * 65536 + ch * 256, bff1 + l * 512 + ch * 256,
                hid, false, true);
            __syncthreads();
            gemmT<256, 260, 32, 4, 128, 32, 132, 32, 32>(
                hid, Wff2 + (size_t)l * 65536 + (size_t)ch * 32768,
                ch == 0 ? (bff2 + l * 128) : nullptr, Vb, ch != 0, false);
            __syncthreads();
        }
        for (int idx = tid; idx < 2048; idx += 256)
            xs[idx] += Vb[(idx >> 7) * 132 + (idx & 127)];
        __syncthreads();
        ln256(xs, ln2s + l * 128, ln2b + l * 128);
    }
    for (int idx = tid; idx < 2048; idx += 256)
        out[(size_t)m * 2048 + idx] = xs[idx];
}

extern "C" void kernel_launch(void* const* d_in, const int* in_sizes, int n_in,
                              void* d_out, int out_size, void* d_ws, size_t ws_size,
                              hipStream_t stream) {
    (void)in_sizes; (void)n_in; (void)out_size; (void)ws_size;
    const int*   ego  = (const int*)d_in[0];
    const float* pos  = (const float*)d_in[1];
    const float* adj  = (const float*)d_in[2];
    const float* g1W  = (const float*)d_in[3];
    const float* g1as = (const float*)d_in[4];
    const float* g1ad = (const float*)d_in[5];
    const float* g1b  = (const float*)d_in[6];
    const float* gW   = (const float*)d_in[7];
    const float* gas  = (const float*)d_in[8];
    const float* gad  = (const float*)d_in[9];
    const float* gb   = (const float*)d_in[10];
    const float* Wqkv = (const float*)d_in[11];
    const float* bqkv = (const float*)d_in[12];
    const float* Wo   = (const float*)d_in[13];
    const float* bo   = (const float*)d_in[14];
    const float* l1s  = (const float*)d_in[15];
    const float* l1b  = (const float*)d_in[16];
    const float* l2s  = (const float*)d_in[17];
    const float* l2b  = (const float*)d_in[18];
    const float* Wff1 = (const float*)d_in[19];
    const float* bff1 = (const float*)d_in[20];
    const float* Wff2 = (const float*)d_in[21];
    const float* bff2 = (const float*)d_in[22];

    float* ws  = (float*)d_ws;
    float* x0  = ws;                       // 2,097,152 f
    float* x1  = x0 + 2097152;             // 2,097,152 f
    float* hb  = x1 + 2097152;             // 8,388,608 f
    float* ssb = hb + 8388608;             // 65,536 f
    float* sdb = ssb + 65536;              // 65,536 f
    float* mfl = sdb + 65536;              // 16,384 f
    int*   cnt = (int*)(mfl + 16384);      // 16,384 i
    int*   nbr = cnt + 16384;              // 1,048,576 i   (total ~55.2 MB)

    k_init<<<64, 256, 0, stream>>>(ego, mfl, cnt);
    k_edges<<<256, 256, 0, stream>>>(adj, mfl, cnt, nbr);

    // GAT layer 1 (F=2), projection + ss/sd fused
    k_gat1<<<NROWS, 128, 0, stream>>>(pos, g1W, g1as, g1ad, hb, ssb, sdb);
    k_agg<<<NROWS, 128, 0, stream>>>(hb, ssb, sdb, cnt, nbr, mfl, g1b, x0);

    float* xin = x0; float* xout = x1;
    for (int L = 0; L < 5; ++L) {
        k_gat_h<<<1024, 256, 0, stream>>>(xin, gW + (size_t)L * 65536,
                                          gas + L * 512, gad + L * 512, hb, ssb, sdb);
        k_agg<<<NROWS, 128, 0, stream>>>(hb, ssb, sdb, cnt, nbr, mfl, gb + L * 128, xout);
        float* tmp = xin; xin = xout; xout = tmp;
    }

    k_tf<<<MM, 256, 0, stream>>>(xin, Wqkv, bqkv, Wo, bo, l1s, l1b, l2s, l2b,
                                 Wff1, bff1, Wff2, bff2, (float*)d_out);
}

// Round 7
// 1025.298 us; speedup vs baseline: 1.9804x; 1.9804x over previous
//
#include <hip/hip_runtime.h>
#include <hip/hip_bf16.h>

// Problem constants
#define TT 16
#define MM 1024
#define HDIM 128
#define NHEADS 4
#define NROWS (TT*MM)          // 16384
#define MAXDEG 64

typedef __bf16 bf16x8 __attribute__((ext_vector_type(8)));
typedef float f32x4 __attribute__((ext_vector_type(4)));

__device__ __forceinline__ unsigned short f2b(float x) {   // fp32 -> bf16 RNE
    unsigned u = __float_as_uint(x);
    u += 0x7fff + ((u >> 16) & 1);
    return (unsigned short)(u >> 16);
}

// ---------------- mask + neighbor-list build ----------------
__global__ __launch_bounds__(256) void k_init(const int* __restrict__ ego,
                                              float* __restrict__ mfl,
                                              int* __restrict__ cnt) {
    int idx = blockIdx.x * 256 + threadIdx.x;   // < 16384
    int t = idx >> 10, i = idx & 1023;
    int b = i >> 8, n = i & 255;
    mfl[idx] = ego[b * (TT * 256) + t * 256 + n] ? 1.f : 0.f;
    cnt[idx] = 0;
}

__global__ __launch_bounds__(256) void k_edges(const float* __restrict__ adj,
                                               const float* __restrict__ mfl,
                                               int* __restrict__ cnt,
                                               int* __restrict__ nbr) {
    int bid = blockIdx.x;            // 256 blocks: t(16) x jc(4) x ic(4)
    int t = bid >> 4, jc = (bid >> 2) & 3, ic = bid & 3;
    int tid = threadIdx.x;
    int i = ic * 256 + tid;
    int row = t * MM + i;
    __shared__ float ms[256];
    int j0 = jc * 256;
    ms[tid] = mfl[t * MM + j0 + tid];
    __syncthreads();
    float mi = mfl[row];
    if (mi == 0.f) return;
    const float* at = adj + (size_t)t * MM * MM;
    for (int jj = 0; jj < 256; ++jj) {
        int j = j0 + jj;
        bool e;
        if (j == i) e = true;                                   // self-loop
        else e = (at[(size_t)j * MM + i] != 0.f) && (ms[jj] != 0.f);
        if (e) {
            int pos = atomicAdd(&cnt[row], 1);
            if (pos < MAXDEG) nbr[(size_t)row * MAXDEG + pos] = j;
        }
    }
}

// ---------------- weight prep: fp32 -> bf16 MFMA B-fragment order ----------------
// Frag layout per matrix: [nt][ks][lane][j] ; value = W[k=ks*32+(lane>>4)*8+j][c=nt*16+(lane&15)]
// Layer blob (bf16 elems): QKV @0 (24nt x 4ks), Wo @49152 (8x4), FF1 @65536 (32x4), FF2 @131072 (8x16)
__global__ __launch_bounds__(256) void k_prep(const float* __restrict__ Wqkv,
                                              const float* __restrict__ Wo,
                                              const float* __restrict__ Wff1,
                                              const float* __restrict__ Wff2,
                                              unsigned short* __restrict__ Wb) {
    int o = blockIdx.x * 256 + threadIdx.x;     // frag-unit (8 elems) index, < 122880
    int l = o / 24576, r = o % 24576;
    const float* src; int cs;
    if (r < 6144) {                 // QKV
        int nt = r >> 8, rem = r & 255, ks = rem >> 6, lane = rem & 63;
        int mt = nt >> 3, cc = nt & 7;
        int k = ks * 32 + ((lane >> 4) << 3), c = cc * 16 + (lane & 15);
        src = Wqkv + ((size_t)(l * 3 + mt) * 128 + k) * 128 + c; cs = 128;
    } else if (r < 8192) {          // Wo
        int u = r - 6144, nt = u >> 8, rem = u & 255, ks = rem >> 6, lane = rem & 63;
        int k = ks * 32 + ((lane >> 4) << 3), c = nt * 16 + (lane & 15);
        src = Wo + (size_t)l * 16384 + (size_t)k * 128 + c; cs = 128;
    } else if (r < 16384) {         // FF1
        int u = r - 8192, nt = u >> 8, rem = u & 255, ks = rem >> 6, lane = rem & 63;
        int k = ks * 32 + ((lane >> 4) << 3), c = nt * 16 + (lane & 15);
        src = Wff1 + (size_t)l * 65536 + (size_t)k * 512 + c; cs = 512;
    } else {                        // FF2
        int u = r - 16384, nt = u >> 10, rem = u & 1023, ks = rem >> 6, lane = rem & 63;
        int k = ks * 32 + ((lane >> 4) << 3), c = nt * 16 + (lane & 15);
        src = Wff2 + (size_t)l * 65536 + (size_t)k * 128 + c; cs = 128;
    }
    unsigned v[4];
#pragma unroll
    for (int j = 0; j < 4; ++j)
        v[j] = (unsigned)f2b(src[(2 * j) * (size_t)cs]) |
               ((unsigned)f2b(src[(2 * j + 1) * (size_t)cs]) << 16);
    *(uint4*)(Wb + (size_t)o * 8) = make_uint4(v[0], v[1], v[2], v[3]);
}

// ---------------- GAT layer 1: projection (F=2) + fused ss/sd ----------------
__global__ __launch_bounds__(128) void k_gat1(const float* __restrict__ x,
                                              const float* __restrict__ W,
                                              const float* __restrict__ asrc,
                                              const float* __restrict__ adst,
                                              float* __restrict__ h,
                                              float* __restrict__ ss,
                                              float* __restrict__ sd) {
    int bid = blockIdx.x;
    int row = ((bid & 7) << 11) + (bid >> 3);   // XCD-locality swizzle
    int tid = threadIdx.x;
    float x0 = x[row * 2], x1 = x[row * 2 + 1];
    float s4[4], d4[4];
#pragma unroll
    for (int hh = 0; hh < 4; ++hh) {
        int o = hh * 128 + tid;
        float v = x0 * W[o] + x1 * W[512 + o];
        h[(size_t)row * 512 + o] = v;
        s4[hh] = v * asrc[o];
        d4[hh] = v * adst[o];
    }
#pragma unroll
    for (int hh = 0; hh < 4; ++hh)
        for (int off = 32; off; off >>= 1) {
            s4[hh] += __shfl_down(s4[hh], off, 64);
            d4[hh] += __shfl_down(d4[hh], off, 64);
        }
    __shared__ float red[2][2][4];
    if ((tid & 63) == 0) {
        int w = tid >> 6;
#pragma unroll
        for (int hh = 0; hh < 4; ++hh) { red[w][0][hh] = s4[hh]; red[w][1][hh] = d4[hh]; }
    }
    __syncthreads();
    if (tid < 4) ss[row * 4 + tid] = red[0][0][tid] + red[1][0][tid];
    else if (tid < 8) sd[row * 4 + tid - 4] = red[0][1][tid - 4] + red[1][1][tid - 4];
}

// ---------------- GEMM with acc export (for k_gat_h): [16,K]@[K,OTILE*128] ----------------
template <int K, int OTILE, int WKS, int WOS, int ORS, int OOS>
__device__ __forceinline__ void gemm16e(const float* __restrict__ Xs,
                                        const float* __restrict__ W,
                                        float* __restrict__ Out,
                                        float (&acc)[8][OTILE]) {
    const int tid = threadIdx.x;
    const int og = tid & 127;
    const int r0 = (tid >> 7) * 8;
#pragma unroll
    for (int r = 0; r < 8; ++r)
#pragma unroll
        for (int ot = 0; ot < OTILE; ++ot) acc[r][ot] = 0.f;
    for (int k = 0; k < K; k += 4) {
        float4 xv[8];
#pragma unroll
        for (int r = 0; r < 8; ++r)
            xv[r] = *(const float4*)(Xs + (r0 + r) * K + k);
#pragma unroll
        for (int ot = 0; ot < OTILE; ++ot) {
            const float* wp = W + ot * WOS + og;
            float w0 = wp[(k + 0) * WKS];
            float w1 = wp[(k + 1) * WKS];
            float w2 = wp[(k + 2) * WKS];
            float w3 = wp[(k + 3) * WKS];
#pragma unroll
            for (int r = 0; r < 8; ++r)
                acc[r][ot] += xv[r].x * w0 + xv[r].y * w1 + xv[r].z * w2 + xv[r].w * w3;
        }
    }
#pragma unroll
    for (int ot = 0; ot < OTILE; ++ot)
#pragma unroll
        for (int r = 0; r < 8; ++r)
            Out[(r0 + r) * ORS + ot * OOS + og] = acc[r][ot];
}

// ---------------- GAT layers 2-6: projection (F=128) + fused ss/sd ----------------
__global__ __launch_bounds__(256, 4) void k_gat_h(const float* __restrict__ x,
                                                  const float* __restrict__ W,
                                                  const float* __restrict__ asrc,
                                                  const float* __restrict__ adst,
                                                  float* __restrict__ h,
                                                  float* __restrict__ ss,
                                                  float* __restrict__ sd) {
    __shared__ __align__(16) float Xs[2048];
    __shared__ float sred[4][8][4], dred[4][8][4];
    int bid = blockIdx.x;
    int row0 = (((bid & 7) << 7) + (bid >> 3)) * 16;   // band swizzle, same XCD mapping
    int tid = threadIdx.x;
    for (int idx = tid; idx < 2048; idx += 256)
        Xs[idx] = x[(size_t)row0 * 128 + idx];
    __syncthreads();
    float acc[8][4];
    gemm16e<128, 4, 512, 128, 512, 128>(Xs, W, h + (size_t)row0 * 512, acc);
    int og = tid & 127, wave = tid >> 6;
#pragma unroll
    for (int r = 0; r < 8; ++r) {
#pragma unroll
        for (int ot = 0; ot < 4; ++ot) {
            float s = acc[r][ot] * asrc[ot * 128 + og];
            float d = acc[r][ot] * adst[ot * 128 + og];
#pragma unroll
            for (int off = 32; off; off >>= 1) {
                s += __shfl_xor(s, off, 64);
                d += __shfl_xor(d, off, 64);
            }
            if ((tid & 63) == 0) { sred[wave][r][ot] = s; dred[wave][r][ot] = d; }
        }
    }
    __syncthreads();
    if (tid < 64) {
        int r = tid >> 2, hh = tid & 3;
        int w0 = (r >> 3) * 2, rr = r & 7;
        ss[(row0 + r) * 4 + hh] = sred[w0][rr][hh] + sred[w0 + 1][rr][hh];
        sd[(row0 + r) * 4 + hh] = dred[w0][rr][hh] + dred[w0 + 1][rr][hh];
    }
}

// ---------------- GAT aggregation (segment softmax + gather), XCD-swizzled ----------------
__global__ __launch_bounds__(128) void k_agg(const float* __restrict__ h,
                                             const float* __restrict__ ss,
                                             const float* __restrict__ sd,
                                             const int* __restrict__ cnt,
                                             const int* __restrict__ nbr,
                                             const float* __restrict__ mfl,
                                             const float* __restrict__ bias,
                                             float* __restrict__ xo) {
    int bid = blockIdx.x;
    int row = ((bid & 7) << 11) + (bid >> 3);   // same-t rows colocate per XCD
    int tid = threadIdx.x;
    int t = row >> 10;
    if (mfl[row] == 0.f) { xo[(size_t)row * 128 + tid] = 0.f; return; }
    int c = cnt[row]; if (c > MAXDEG) c = MAXDEG;
    __shared__ int nb[MAXDEG];
    __shared__ float al[MAXDEG][4];
    if (tid < c) nb[tid] = nbr[(size_t)row * MAXDEG + tid];
    __syncthreads();
    for (int idx = tid; idx < c * 4; idx += 128) {
        int n = idx >> 2, hh = idx & 3, j = nb[n];
        float lg = sd[row * 4 + hh] + ss[(t * MM + j) * 4 + hh];
        al[n][hh] = lg > 0.f ? lg : 0.2f * lg;   // leaky_relu 0.2
    }
    __syncthreads();
    if (tid < 4) {
        float mx = -1e30f;
        for (int n = 0; n < c; ++n) mx = fmaxf(mx, al[n][tid]);
        float s = 0.f;
        for (int n = 0; n < c; ++n) { float e = __expf(al[n][tid] - mx); al[n][tid] = e; s += e; }
        float inv = 1.f / s;
        for (int n = 0; n < c; ++n) al[n][tid] *= inv;
    }
    __syncthreads();
    float a0 = 0, a1 = 0, a2 = 0, a3 = 0;
    for (int n = 0; n < c; ++n) {
        int j = nb[n];
        const float* hp = h + ((size_t)(t * MM + j)) * 512 + tid;
        a0 += al[n][0] * hp[0];
        a1 += al[n][1] * hp[128];
        a2 += al[n][2] * hp[256];
        a3 += al[n][3] * hp[384];
    }
    float v = 0.25f * (a0 + a1 + a2 + a3) + bias[tid];
    xo[(size_t)row * 128 + tid] = fmaxf(v, 0.f);
}

// ---------------- in-place LayerNorm, 16 rows x 128, 256 threads ----------------
__device__ __forceinline__ void ln256(float* xs, const float* s, const float* b) {
    int tid = threadIdx.x, row = tid >> 4, lane = tid & 15;
    float* xr = xs + row * 128;
    float sum = 0.f;
#pragma unroll
    for (int k2 = 0; k2 < 8; ++k2) sum += xr[lane + 16 * k2];
#pragma unroll
    for (int off = 8; off; off >>= 1) sum += __shfl_xor(sum, off, 16);
    float mean = sum * (1.f / 128.f);
    float vs = 0.f;
#pragma unroll
    for (int k2 = 0; k2 < 8; ++k2) { float d = xr[lane + 16 * k2] - mean; vs += d * d; }
#pragma unroll
    for (int off = 8; off; off >>= 1) vs += __shfl_xor(vs, off, 16);
    float rstd = rsqrtf(vs * (1.f / 128.f) + 1e-5f);
#pragma unroll
    for (int k2 = 0; k2 < 8; ++k2) {
        int d = lane + 16 * k2;
        float v = (xr[d] - mean) * rstd;
        xr[d] = v * s[d] + b[d];
    }
    __syncthreads();
}

// ---------------- 5-layer transformer: MFMA bf16 GEMMs, fp32 attention/LN ----------------
// LDS = 2048(xs) + 3*2112(Qf,Kf,Vf) + 1024(sb) + 1088(xb16) = 10496 fl = 41984 B -> 3 blk/CU.
// hid16 (16x520 bf16) overlays Qf+Kf (dead during FF).
__global__ __launch_bounds__(256, 3) void k_tf(const float* __restrict__ xg,
        const unsigned short* __restrict__ Wb,
        const float* __restrict__ bqkv, const float* __restrict__ bo,
        const float* __restrict__ ln1s, const float* __restrict__ ln1b,
        const float* __restrict__ ln2s, const float* __restrict__ ln2b,
        const float* __restrict__ bff1, const float* __restrict__ bff2,
        float* __restrict__ out) {
    __shared__ __align__(16) float smem[10496];
    float* xs = smem;                  // [16][128] residual fp32
    float* Qf = smem + 2048;           // [16][132]
    float* Kf = smem + 4160;           // [16][132]
    float* Vf = smem + 6272;           // [16][132]
    float* sb = smem + 8384;           // [16tk][64] transposed scores
    unsigned short* xb16  = (unsigned short*)(smem + 9408); // [16][136] bf16 A-operand / Ob16
    unsigned short* hid16 = (unsigned short*)(smem + 2048); // [16][520] bf16, overlays Qf+Kf
    const int m = blockIdx.x, tid = threadIdx.x;
    const int lane = tid & 63, w = tid >> 6;
    const int mrow = lane & 15, quad = lane >> 4;

    // load + sinusoidal PE
    for (int idx = tid; idx < 2048; idx += 256) {
        int t = idx >> 7, d = idx & 127, jj = d >> 1;
        float arg = (float)t * expf(-(float)(2 * jj) * (9.210340371976184f / 128.f));
        float pe = (d & 1) ? cosf(arg) : sinf(arg);
        xs[idx] = xg[(size_t)t * (MM * HDIM) + (size_t)m * HDIM + d] + pe;
    }
    __syncthreads();

    const int crow = tid >> 4, ccb = (tid & 15) * 8;   // xs->xb16 conversion slots
    for (int l = 0; l < 5; ++l) {
        const unsigned short* Wl = Wb + (size_t)l * 196608;
        // ---- xs -> xb16 ----
        {
            const float* xp = xs + crow * 128 + ccb;
            unsigned v[4];
#pragma unroll
            for (int j = 0; j < 4; ++j)
                v[j] = (unsigned)f2b(xp[2 * j]) | ((unsigned)f2b(xp[2 * j + 1]) << 16);
            *(uint4*)(xb16 + crow * 136 + ccb) = make_uint4(v[0], v[1], v[2], v[3]);
        }
        __syncthreads();
        // ---- QKV via MFMA: 24 n-tiles, wave w does nt = 6w..6w+5 ----
        {
            bf16x8 af[4];
#pragma unroll
            for (int ks = 0; ks < 4; ++ks)
                af[ks] = *(const bf16x8*)(xb16 + mrow * 136 + ks * 32 + quad * 8);
            f32x4 acc[6];
#pragma unroll
            for (int i = 0; i < 6; ++i) acc[i] = (f32x4){0.f, 0.f, 0.f, 0.f};
#pragma unroll
            for (int i = 0; i < 6; ++i) {
                int nt = w * 6 + i;
                const unsigned short* bp = Wl + (size_t)(nt * 4) * 512 + lane * 8;
#pragma unroll
                for (int ks = 0; ks < 4; ++ks) {
                    bf16x8 bf = *(const bf16x8*)(bp + ks * 512);
                    acc[i] = __builtin_amdgcn_mfma_f32_16x16x32_bf16(af[ks], bf, acc[i], 0, 0, 0);
                }
            }
#pragma unroll
            for (int i = 0; i < 6; ++i) {
                int nt = w * 6 + i, mt = nt >> 3, cc = nt & 7;
                int col = cc * 16 + mrow;
                float bb = bqkv[l * 384 + mt * 128 + col];
                float* dst = (mt == 0) ? Qf : (mt == 1) ? Kf : Vf;
#pragma unroll
                for (int r = 0; r < 4; ++r)
                    dst[(quad * 4 + r) * 132 + col] = acc[i][r] + bb;
            }
        }
        __syncthreads();
        // ---- scores (fp32 VALU): thread = (hh, tq, tk0..tk0+3) ----
        {
            int hh = tid >> 6, tq = (tid >> 2) & 15, tk0 = (tid & 3) * 4;
            const float* qp = Qf + tq * 132 + hh * 32;
            float a[4] = {0.f, 0.f, 0.f, 0.f};
#pragma unroll
            for (int d = 0; d < 8; ++d) {
                float4 q4 = *(const float4*)(qp + 4 * d);
#pragma unroll
                for (int j = 0; j < 4; ++j) {
                    float4 k4 = *(const float4*)(Kf + (tk0 + j) * 132 + hh * 32 + 4 * d);
                    a[j] += q4.x * k4.x + q4.y * k4.y + q4.z * k4.z + q4.w * k4.w;
                }
            }
#pragma unroll
            for (int j = 0; j < 4; ++j)
                sb[(tk0 + j) * 64 + hh * 16 + tq] = a[j] * 0.17677669529663687f;
        }
        __syncthreads();
        if (tid < 64) {   // softmax per (hh,tq) column
            float mx = -1e30f;
#pragma unroll
            for (int u = 0; u < 16; ++u) mx = fmaxf(mx, sb[u * 64 + tid]);
            float s = 0.f;
#pragma unroll
            for (int u = 0; u < 16; ++u) { float e = __expf(sb[u * 64 + tid] - mx); sb[u * 64 + tid] = e; s += e; }
            float inv = 1.f / s;
#pragma unroll
            for (int u = 0; u < 16; ++u) sb[u * 64 + tid] *= inv;
        }
        __syncthreads();
        // ---- O = P @ V (fp32) -> xb16 (as bf16 Ob) ----
        {
            int o = tid & 127, r0p = (tid >> 7) * 8, hh = o >> 5;
            float accp[8] = {0, 0, 0, 0, 0, 0, 0, 0};
            for (int u = 0; u < 16; ++u) {
                float vv = Vf[u * 132 + o];
                const float* pp = sb + u * 64 + hh * 16 + r0p;
#pragma unroll
                for (int r = 0; r < 8; ++r) accp[r] += pp[r] * vv;
            }
#pragma unroll
            for (int r = 0; r < 8; ++r)
                xb16[(r0p + r) * 136 + o] = f2b(accp[r]);
        }
        __syncthreads();
        // ---- Wo via MFMA: 8 n-tiles, wave w does nt = 2w, 2w+1; accumulate into xs ----
        {
            bf16x8 af[4];
#pragma unroll
            for (int ks = 0; ks < 4; ++ks)
                af[ks] = *(const bf16x8*)(xb16 + mrow * 136 + ks * 32 + quad * 8);
            f32x4 acc[2];
            acc[0] = (f32x4){0.f, 0.f, 0.f, 0.f};
            acc[1] = (f32x4){0.f, 0.f, 0.f, 0.f};
            const unsigned short* Ws = Wl + 49152;
#pragma unroll
            for (int i = 0; i < 2; ++i) {
                int nt = w * 2 + i;
#pragma unroll
                for (int ks = 0; ks < 4; ++ks) {
                    bf16x8 bf = *(const bf16x8*)(Ws + (size_t)((nt * 4 + ks) * 64 + lane) * 8);
                    acc[i] = __builtin_amdgcn_mfma_f32_16x16x32_bf16(af[ks], bf, acc[i], 0, 0, 0);
                }
            }
#pragma unroll
            for (int i = 0; i < 2; ++i) {
                int col = (w * 2 + i) * 16 + mrow;
                float bb = bo[l * 128 + col];
#pragma unroll
                for (int r = 0; r < 4; ++r)
                    xs[(quad * 4 + r) * 128 + col] += acc[i][r] + bb;
            }
        }
        __syncthreads();
        ln256(xs, ln1s + l * 128, ln1b + l * 128);
        // ---- xs -> xb16 (post-LN1) ----
        {
            const float* xp = xs + crow * 128 + ccb;
            unsigned v[4];
#pragma unroll
            for (int j = 0; j < 4; ++j)
                v[j] = (unsigned)f2b(xp[2 * j]) | ((unsigned)f2b(xp[2 * j + 1]) << 16);
            *(uint4*)(xb16 + crow * 136 + ccb) = make_uint4(v[0], v[1], v[2], v[3]);
        }
        __syncthreads();
        // ---- FF1 via MFMA: 32 n-tiles, wave w does nt = 8w..8w+7; relu -> hid16 ----
        {
            bf16x8 af[4];
#pragma unroll
            for (int ks = 0; ks < 4; ++ks)
                af[ks] = *(const bf16x8*)(xb16 + mrow * 136 + ks * 32 + quad * 8);
            f32x4 acc[8];
#pragma unroll
            for (int i = 0; i < 8; ++i) acc[i] = (f32x4){0.f, 0.f, 0.f, 0.f};
            const unsigned short* Ws = Wl + 65536;
#pragma unroll
            for (int i = 0; i < 8; ++i) {
                int nt = w * 8 + i;
#pragma unroll
                for (int ks = 0; ks < 4; ++ks) {
                    bf16x8 bf = *(const bf16x8*)(Ws + (size_t)((nt * 4 + ks) * 64 + lane) * 8);
                    acc[i] = __builtin_amdgcn_mfma_f32_16x16x32_bf16(af[ks], bf, acc[i], 0, 0, 0);
                }
            }
#pragma unroll
            for (int i = 0; i < 8; ++i) {
                int col = (w * 8 + i) * 16 + mrow;
                float bb = bff1[l * 512 + col];
#pragma unroll
                for (int r = 0; r < 4; ++r) {
                    float v = fmaxf(acc[i][r] + bb, 0.f);
                    hid16[(quad * 4 + r) * 520 + col] = f2b(v);
                }
            }
        }
        __syncthreads();
        // ---- FF2 via MFMA: 8 n-tiles x 16 k-steps; accumulate into xs ----
        {
            f32x4 a0 = (f32x4){0.f, 0.f, 0.f, 0.f};
            f32x4 a1 = (f32x4){0.f, 0.f, 0.f, 0.f};
            const unsigned short* Ws = Wl + 131072;
            int nt0 = w * 2, nt1 = w * 2 + 1;
#pragma unroll
            for (int ks = 0; ks < 16; ++ks) {
                bf16x8 af = *(const bf16x8*)(hid16 + mrow * 520 + ks * 32 + quad * 8);
                bf16x8 b0 = *(const bf16x8*)(Ws + (size_t)((nt0 * 16 + ks) * 64 + lane) * 8);
                bf16x8 b1 = *(const bf16x8*)(Ws + (size_t)((nt1 * 16 + ks) * 64 + lane) * 8);
                a0 = __builtin_amdgcn_mfma_f32_16x16x32_bf16(af, b0, a0, 0, 0, 0);
                a1 = __builtin_amdgcn_mfma_f32_16x16x32_bf16(af, b1, a1, 0, 0, 0);
            }
            int col0 = nt0 * 16 + mrow, col1 = nt1 * 16 + mrow;
            float bb0 = bff2[l * 128 + col0], bb1 = bff2[l * 128 + col1];
#pragma unroll
            for (int r = 0; r < 4; ++r) {
                xs[(quad * 4 + r) * 128 + col0] += a0[r] + bb0;
                xs[(quad * 4 + r) * 128 + col1] += a1[r] + bb1;
            }
        }
        __syncthreads();
        ln256(xs, ln2s + l * 128, ln2b + l * 128);
    }
    for (int idx = tid; idx < 2048; idx += 256)
        out[(size_t)m * 2048 + idx] = xs[idx];
}

extern "C" void kernel_launch(void* const* d_in, const int* in_sizes, int n_in,
                              void* d_out, int out_size, void* d_ws, size_t ws_size,
                              hipStream_t stream) {
    (void)in_sizes; (void)n_in; (void)out_size; (void)ws_size;
    const int*   ego  = (const int*)d_in[0];
    const float* pos  = (const float*)d_in[1];
    const float* adj  = (const float*)d_in[2];
    const float* g1W  = (const float*)d_in[3];
    const float* g1as = (const float*)d_in[4];
    const float* g1ad = (const float*)d_in[5];
    const float* g1b  = (const float*)d_in[6];
    const float* gW   = (const float*)d_in[7];
    const float* gas  = (const float*)d_in[8];
    const float* gad  = (const float*)d_in[9];
    const float* gb   = (const float*)d_in[10];
    const float* Wqkv = (const float*)d_in[11];
    const float* bqkv = (const float*)d_in[12];
    const float* Wo   = (const float*)d_in[13];
    const float* bo   = (const float*)d_in[14];
    const float* l1s  = (const float*)d_in[15];
    const float* l1b  = (const float*)d_in[16];
    const float* l2s  = (const float*)d_in[17];
    const float* l2b  = (const float*)d_in[18];
    const float* Wff1 = (const float*)d_in[19];
    const float* bff1 = (const float*)d_in[20];
    const float* Wff2 = (const float*)d_in[21];
    const float* bff2 = (const float*)d_in[22];

    float* ws  = (float*)d_ws;
    float* x0  = ws;                       // 2,097,152 f
    float* x1  = x0 + 2097152;             // 2,097,152 f
    float* hb  = x1 + 2097152;             // 8,388,608 f
    float* ssb = hb + 8388608;             // 65,536 f
    float* sdb = ssb + 65536;              // 65,536 f
    float* mfl = sdb + 65536;              // 16,384 f
    int*   cnt = (int*)(mfl + 16384);      // 16,384 i
    int*   nbr = cnt + 16384;              // 1,048,576 i
    unsigned short* Wb16 = (unsigned short*)(nbr + 1048576);  // 983,040 bf16 (~1.9 MB)

    k_prep<<<480, 256, 0, stream>>>(Wqkv, Wo, Wff1, Wff2, Wb16);
    k_init<<<64, 256, 0, stream>>>(ego, mfl, cnt);
    k_edges<<<256, 256, 0, stream>>>(adj, mfl, cnt, nbr);

    // GAT layer 1 (F=2), projection + ss/sd fused
    k_gat1<<<NROWS, 128, 0, stream>>>(pos, g1W, g1as, g1ad, hb, ssb, sdb);
    k_agg<<<NROWS, 128, 0, stream>>>(hb, ssb, sdb, cnt, nbr, mfl, g1b, x0);

    float* xin = x0; float* xout = x1;
    for (int L = 0; L < 5; ++L) {
        k_gat_h<<<1024, 256, 0, stream>>>(xin, gW + (size_t)L * 65536,
                                          gas + L * 512, gad + L * 512, hb, ssb, sdb);
        k_agg<<<NROWS, 128, 0, stream>>>(hb, ssb, sdb, cnt, nbr, mfl, gb + L * 128, xout);
        float* tmp = xin; xin = xout; xout = tmp;
    }

    k_tf<<<MM, 256, 0, stream>>>(xin, Wb16, bqkv, bo, l1s, l1b, l2s, l2b,
                                 bff1, bff2, (float*)d_out);
}

// Round 8
// 822.307 us; speedup vs baseline: 2.4693x; 1.2469x over previous
//
#include <hip/hip_runtime.h>
#include <hip/hip_bf16.h>

// Problem constants
#define TT 16
#define MM 1024
#define HDIM 128
#define NHEADS 4
#define NROWS (TT*MM)          // 16384
#define MAXDEG 64

typedef __bf16 bf16x8 __attribute__((ext_vector_type(8)));
typedef float f32x4 __attribute__((ext_vector_type(4)));

__device__ __forceinline__ unsigned short f2b(float x) {   // fp32 -> bf16 RNE
    unsigned u = __float_as_uint(x);
    u += 0x7fff + ((u >> 16) & 1);
    return (unsigned short)(u >> 16);
}
__device__ __forceinline__ float bu2f(unsigned short u) {
    return __uint_as_float(((unsigned)u) << 16);
}

// ---------------- mask + neighbor-list build ----------------
__global__ __launch_bounds__(256) void k_init(const int* __restrict__ ego,
                                              float* __restrict__ mfl,
                                              int* __restrict__ cnt) {
    int idx = blockIdx.x * 256 + threadIdx.x;   // < 16384
    int t = idx >> 10, i = idx & 1023;
    int b = i >> 8, n = i & 255;
    mfl[idx] = ego[b * (TT * 256) + t * 256 + n] ? 1.f : 0.f;
    cnt[idx] = 0;
}

__global__ __launch_bounds__(256) void k_edges(const float* __restrict__ adj,
                                               const float* __restrict__ mfl,
                                               int* __restrict__ cnt,
                                               int* __restrict__ nbr) {
    int bid = blockIdx.x;            // 256 blocks: t(16) x jc(4) x ic(4)
    int t = bid >> 4, jc = (bid >> 2) & 3, ic = bid & 3;
    int tid = threadIdx.x;
    int i = ic * 256 + tid;
    int row = t * MM + i;
    __shared__ float ms[256];
    int j0 = jc * 256;
    ms[tid] = mfl[t * MM + j0 + tid];
    __syncthreads();
    float mi = mfl[row];
    if (mi == 0.f) return;
    const float* at = adj + (size_t)t * MM * MM;
    for (int jj = 0; jj < 256; ++jj) {
        int j = j0 + jj;
        bool e;
        if (j == i) e = true;                                   // self-loop
        else e = (at[(size_t)j * MM + i] != 0.f) && (ms[jj] != 0.f);
        if (e) {
            int pos = atomicAdd(&cnt[row], 1);
            if (pos < MAXDEG) nbr[(size_t)row * MAXDEG + pos] = j;
        }
    }
}

// ---------------- weight prep: fp32 -> bf16 MFMA B-fragment order ----------------
// Transformer blob (o < 122880): QKV/Wo/FF1/FF2 per layer as in R7.
// GAT blob (o >= 122880): gW[5][128][512], 32nt x 4ks per layer.
__global__ __launch_bounds__(256) void k_prep(const float* __restrict__ Wqkv,
                                              const float* __restrict__ Wo,
                                              const float* __restrict__ Wff1,
                                              const float* __restrict__ Wff2,
                                              const float* __restrict__ gW,
                                              unsigned short* __restrict__ Wb) {
    int o = blockIdx.x * 256 + threadIdx.x;     // frag-unit (8 elems) index, < 163840
    const float* src; int cs;
    if (o < 122880) {
        int l = o / 24576, r = o % 24576;
        if (r < 6144) {                 // QKV
            int nt = r >> 8, rem = r & 255, ks = rem >> 6, lane = rem & 63;
            int mt = nt >> 3, cc = nt & 7;
            int k = ks * 32 + ((lane >> 4) << 3), c = cc * 16 + (lane & 15);
            src = Wqkv + ((size_t)(l * 3 + mt) * 128 + k) * 128 + c; cs = 128;
        } else if (r < 8192) {          // Wo
            int u = r - 6144, nt = u >> 8, rem = u & 255, ks = rem >> 6, lane = rem & 63;
            int k = ks * 32 + ((lane >> 4) << 3), c = nt * 16 + (lane & 15);
            src = Wo + (size_t)l * 16384 + (size_t)k * 128 + c; cs = 128;
        } else if (r < 16384) {         // FF1
            int u = r - 8192, nt = u >> 8, rem = u & 255, ks = rem >> 6, lane = rem & 63;
            int k = ks * 32 + ((lane >> 4) << 3), c = nt * 16 + (lane & 15);
            src = Wff1 + (size_t)l * 65536 + (size_t)k * 512 + c; cs = 512;
        } else {                        // FF2
            int u = r - 16384, nt = u >> 10, rem = u & 1023, ks = rem >> 6, lane = rem & 63;
            int k = ks * 32 + ((lane >> 4) << 3), c = nt * 16 + (lane & 15);
            src = Wff2 + (size_t)l * 65536 + (size_t)k * 128 + c; cs = 128;
        }
    } else {                            // GAT gW
        int u = o - 122880;
        int l = u >> 13, rr = u & 8191;
        int nt = rr >> 8, rem = rr & 255, ks = rem >> 6, lane = rem & 63;
        int k = ks * 32 + ((lane >> 4) << 3), c = nt * 16 + (lane & 15);
        src = gW + (size_t)l * 65536 + (size_t)k * 512 + c; cs = 512;
    }
    unsigned v[4];
#pragma unroll
    for (int j = 0; j < 4; ++j)
        v[j] = (unsigned)f2b(src[(2 * j) * (size_t)cs]) |
               ((unsigned)f2b(src[(2 * j + 1) * (size_t)cs]) << 16);
    *(uint4*)(Wb + (size_t)o * 8) = make_uint4(v[0], v[1], v[2], v[3]);
}

// ---------------- GAT layer 1: projection (F=2) + fused ss/sd; h -> bf16 ----------------
__global__ __launch_bounds__(128) void k_gat1(const float* __restrict__ x,
                                              const float* __restrict__ W,
                                              const float* __restrict__ asrc,
                                              const float* __restrict__ adst,
                                              unsigned short* __restrict__ h16,
                                              float* __restrict__ ss,
                                              float* __restrict__ sd) {
    int bid = blockIdx.x;
    int row = ((bid & 7) << 11) + (bid >> 3);   // XCD-locality swizzle
    int tid = threadIdx.x;
    float x0 = x[row * 2], x1 = x[row * 2 + 1];
    float s4[4], d4[4];
#pragma unroll
    for (int hh = 0; hh < 4; ++hh) {
        int o = hh * 128 + tid;
        float v = x0 * W[o] + x1 * W[512 + o];
        h16[(size_t)row * 512 + o] = f2b(v);
        s4[hh] = v * asrc[o];
        d4[hh] = v * adst[o];
    }
#pragma unroll
    for (int hh = 0; hh < 4; ++hh)
        for (int off = 32; off; off >>= 1) {
            s4[hh] += __shfl_down(s4[hh], off, 64);
            d4[hh] += __shfl_down(d4[hh], off, 64);
        }
    __shared__ float red[2][2][4];
    if ((tid & 63) == 0) {
        int w = tid >> 6;
#pragma unroll
        for (int hh = 0; hh < 4; ++hh) { red[w][0][hh] = s4[hh]; red[w][1][hh] = d4[hh]; }
    }
    __syncthreads();
    if (tid < 4) ss[row * 4 + tid] = red[0][0][tid] + red[1][0][tid];
    else if (tid < 8) sd[row * 4 + tid - 4] = red[0][1][tid - 4] + red[1][1][tid - 4];
}

// ---------------- GAT layers 2-6: MFMA projection + fused ss/sd ----------------
// Block = 16 rows, 4 waves; wave w owns head w (n-tiles 8w..8w+7). 128 MFMAs/block.
__global__ __launch_bounds__(256) void k_gat_h(const unsigned short* __restrict__ x16,
                                               const unsigned short* __restrict__ Wg,
                                               const float* __restrict__ asrc,
                                               const float* __restrict__ adst,
                                               unsigned short* __restrict__ h16,
                                               float* __restrict__ ss,
                                               float* __restrict__ sd) {
    __shared__ __align__(16) unsigned short xb[16 * 136];
    int bid = blockIdx.x;
    int row0 = (((bid & 7) << 7) + (bid >> 3)) * 16;   // band swizzle, XCD mapping
    int tid = threadIdx.x;
    {
        int rr = tid >> 4, cc = (tid & 15) * 8;
        *(uint4*)(xb + rr * 136 + cc) = *(const uint4*)(x16 + (size_t)(row0 + rr) * 128 + cc);
    }
    __syncthreads();
    const int lane = tid & 63, w = tid >> 6;
    const int mrow = lane & 15, quad = lane >> 4;
    bf16x8 af[4];
#pragma unroll
    for (int ks = 0; ks < 4; ++ks)
        af[ks] = *(const bf16x8*)(xb + mrow * 136 + ks * 32 + quad * 8);
    f32x4 acc[8];
#pragma unroll
    for (int i = 0; i < 8; ++i) acc[i] = (f32x4){0.f, 0.f, 0.f, 0.f};
#pragma unroll
    for (int i = 0; i < 8; ++i) {
        int nt = w * 8 + i;
#pragma unroll
        for (int ks = 0; ks < 4; ++ks) {
            bf16x8 bf = *(const bf16x8*)(Wg + (size_t)((nt * 4 + ks) * 64 + lane) * 8);
            acc[i] = __builtin_amdgcn_mfma_f32_16x16x32_bf16(af[ks], bf, acc[i], 0, 0, 0);
        }
    }
    float ps[4] = {0, 0, 0, 0}, pd[4] = {0, 0, 0, 0};
#pragma unroll
    for (int i = 0; i < 8; ++i) {
        int nt = w * 8 + i, col = nt * 16 + mrow;
        float as_ = asrc[col], ad_ = adst[col];
#pragma unroll
        for (int r = 0; r < 4; ++r) {
            float v = acc[i][r];
            h16[(size_t)(row0 + quad * 4 + r) * 512 + col] = f2b(v);
            ps[r] += v * as_; pd[r] += v * ad_;
        }
    }
#pragma unroll
    for (int off = 1; off < 16; off <<= 1)
#pragma unroll
        for (int r = 0; r < 4; ++r) {
            ps[r] += __shfl_xor(ps[r], off, 64);
            pd[r] += __shfl_xor(pd[r], off, 64);
        }
    if (mrow == 0) {
#pragma unroll
        for (int r = 0; r < 4; ++r) {
            int row = row0 + quad * 4 + r;
            ss[row * 4 + w] = ps[r];
            sd[row * 4 + w] = pd[r];
        }
    }
}

// ---------------- GAT aggregation (segment softmax + bf16 gather), XCD-swizzled -----------
__global__ __launch_bounds__(128) void k_agg(const unsigned short* __restrict__ h16,
                                             const float* __restrict__ ss,
                                             const float* __restrict__ sd,
                                             const int* __restrict__ cnt,
                                             const int* __restrict__ nbr,
                                             const float* __restrict__ mfl,
                                             const float* __restrict__ bias,
                                             unsigned short* __restrict__ xo16) {
    int bid = blockIdx.x;
    int row = ((bid & 7) << 11) + (bid >> 3);   // same-t rows colocate per XCD
    int tid = threadIdx.x;
    int t = row >> 10;
    if (mfl[row] == 0.f) { xo16[(size_t)row * 128 + tid] = 0; return; }
    int c = cnt[row]; if (c > MAXDEG) c = MAXDEG;
    __shared__ int nb[MAXDEG];
    __shared__ float al[MAXDEG][4];
    if (tid < c) nb[tid] = nbr[(size_t)row * MAXDEG + tid];
    __syncthreads();
    for (int idx = tid; idx < c * 4; idx += 128) {
        int n = idx >> 2, hh = idx & 3, j = nb[n];
        float lg = sd[row * 4 + hh] + ss[(t * MM + j) * 4 + hh];
        al[n][hh] = lg > 0.f ? lg : 0.2f * lg;   // leaky_relu 0.2
    }
    __syncthreads();
    if (tid < 4) {
        float mx = -1e30f;
        for (int n = 0; n < c; ++n) mx = fmaxf(mx, al[n][tid]);
        float s = 0.f;
        for (int n = 0; n < c; ++n) { float e = __expf(al[n][tid] - mx); al[n][tid] = e; s += e; }
        float inv = 1.f / s;
        for (int n = 0; n < c; ++n) al[n][tid] *= inv;
    }
    __syncthreads();
    float a0 = 0, a1 = 0, a2 = 0, a3 = 0;
    for (int n = 0; n < c; ++n) {
        int j = nb[n];
        const unsigned short* hp = h16 + ((size_t)(t * MM + j)) * 512 + tid;
        a0 += al[n][0] * bu2f(hp[0]);
        a1 += al[n][1] * bu2f(hp[128]);
        a2 += al[n][2] * bu2f(hp[256]);
        a3 += al[n][3] * bu2f(hp[384]);
    }
    float v = 0.25f * (a0 + a1 + a2 + a3) + bias[tid];
    xo16[(size_t)row * 128 + tid] = f2b(fmaxf(v, 0.f));
}

// ---------------- in-place LayerNorm, 16 rows x 128, 256 threads ----------------
__device__ __forceinline__ void ln256(float* xs, const float* s, const float* b) {
    int tid = threadIdx.x, row = tid >> 4, lane = tid & 15;
    float* xr = xs + row * 128;
    float sum = 0.f;
#pragma unroll
    for (int k2 = 0; k2 < 8; ++k2) sum += xr[lane + 16 * k2];
#pragma unroll
    for (int off = 8; off; off >>= 1) sum += __shfl_xor(sum, off, 16);
    float mean = sum * (1.f / 128.f);
    float vs = 0.f;
#pragma unroll
    for (int k2 = 0; k2 < 8; ++k2) { float d = xr[lane + 16 * k2] - mean; vs += d * d; }
#pragma unroll
    for (int off = 8; off; off >>= 1) vs += __shfl_xor(vs, off, 16);
    float rstd = rsqrtf(vs * (1.f / 128.f) + 1e-5f);
#pragma unroll
    for (int k2 = 0; k2 < 8; ++k2) {
        int d = lane + 16 * k2;
        float v = (xr[d] - mean) * rstd;
        xr[d] = v * s[d] + b[d];
    }
    __syncthreads();
}

// ---------------- 5-layer transformer: MFMA bf16 GEMMs, fp32 attention/LN ----------------
__global__ __launch_bounds__(256, 3) void k_tf(const unsigned short* __restrict__ xg,
        const unsigned short* __restrict__ Wb,
        const float* __restrict__ bqkv, const float* __restrict__ bo,
        const float* __restrict__ ln1s, const float* __restrict__ ln1b,
        const float* __restrict__ ln2s, const float* __restrict__ ln2b,
        const float* __restrict__ bff1, const float* __restrict__ bff2,
        float* __restrict__ out) {
    __shared__ __align__(16) float smem[10496];
    float* xs = smem;                  // [16][128] residual fp32
    float* Qf = smem + 2048;           // [16][132]
    float* Kf = smem + 4160;           // [16][132]
    float* Vf = smem + 6272;           // [16][132]
    float* sb = smem + 8384;           // [16tk][64] transposed scores
    unsigned short* xb16  = (unsigned short*)(smem + 9408); // [16][136] bf16 A-operand / Ob16
    unsigned short* hid16 = (unsigned short*)(smem + 2048); // [16][520] bf16, overlays Qf+Kf
    const int m = blockIdx.x, tid = threadIdx.x;
    const int lane = tid & 63, w = tid >> 6;
    const int mrow = lane & 15, quad = lane >> 4;

    // load + sinusoidal PE
    for (int idx = tid; idx < 2048; idx += 256) {
        int t = idx >> 7, d = idx & 127, jj = d >> 1;
        float arg = (float)t * expf(-(float)(2 * jj) * (9.210340371976184f / 128.f));
        float pe = (d & 1) ? cosf(arg) : sinf(arg);
        xs[idx] = bu2f(xg[(size_t)t * (MM * HDIM) + (size_t)m * HDIM + d]) + pe;
    }
    __syncthreads();

    const int crow = tid >> 4, ccb = (tid & 15) * 8;   // xs->xb16 conversion slots
    for (int l = 0; l < 5; ++l) {
        const unsigned short* Wl = Wb + (size_t)l * 196608;
        // ---- xs -> xb16 ----
        {
            const float* xp = xs + crow * 128 + ccb;
            unsigned v[4];
#pragma unroll
            for (int j = 0; j < 4; ++j)
                v[j] = (unsigned)f2b(xp[2 * j]) | ((unsigned)f2b(xp[2 * j + 1]) << 16);
            *(uint4*)(xb16 + crow * 136 + ccb) = make_uint4(v[0], v[1], v[2], v[3]);
        }
        __syncthreads();
        // ---- QKV via MFMA: 24 n-tiles, wave w does nt = 6w..6w+5 ----
        {
            bf16x8 af[4];
#pragma unroll
            for (int ks = 0; ks < 4; ++ks)
                af[ks] = *(const bf16x8*)(xb16 + mrow * 136 + ks * 32 + quad * 8);
            f32x4 acc[6];
#pragma unroll
            for (int i = 0; i < 6; ++i) acc[i] = (f32x4){0.f, 0.f, 0.f, 0.f};
#pragma unroll
            for (int i = 0; i < 6; ++i) {
                int nt = w * 6 + i;
                const unsigned short* bp = Wl + (size_t)(nt * 4) * 512 + lane * 8;
#pragma unroll
                for (int ks = 0; ks < 4; ++ks) {
                    bf16x8 bf = *(const bf16x8*)(bp + ks * 512);
                    acc[i] = __builtin_amdgcn_mfma_f32_16x16x32_bf16(af[ks], bf, acc[i], 0, 0, 0);
                }
            }
#pragma unroll
            for (int i = 0; i < 6; ++i) {
                int nt = w * 6 + i, mt = nt >> 3, cc = nt & 7;
                int col = cc * 16 + mrow;
                float bb = bqkv[l * 384 + mt * 128 + col];
                float* dst = (mt == 0) ? Qf : (mt == 1) ? Kf : Vf;
#pragma unroll
                for (int r = 0; r < 4; ++r)
                    dst[(quad * 4 + r) * 132 + col] = acc[i][r] + bb;
            }
        }
        __syncthreads();
        // ---- scores (fp32 VALU): thread = (hh, tq, tk0..tk0+3) ----
        {
            int hh = tid >> 6, tq = (tid >> 2) & 15, tk0 = (tid & 3) * 4;
            const float* qp = Qf + tq * 132 + hh * 32;
            float a[4] = {0.f, 0.f, 0.f, 0.f};
#pragma unroll
            for (int d = 0; d < 8; ++d) {
                float4 q4 = *(const float4*)(qp + 4 * d);
#pragma unroll
                for (int j = 0; j < 4; ++j) {
                    float4 k4 = *(const float4*)(Kf + (tk0 + j) * 132 + hh * 32 + 4 * d);
                    a[j] += q4.x * k4.x + q4.y * k4.y + q4.z * k4.z + q4.w * k4.w;
                }
            }
#pragma unroll
            for (int j = 0; j < 4; ++j)
                sb[(tk0 + j) * 64 + hh * 16 + tq] = a[j] * 0.17677669529663687f;
        }
        __syncthreads();
        if (tid < 64) {   // softmax per (hh,tq) column
            float mx = -1e30f;
#pragma unroll
            for (int u = 0; u < 16; ++u) mx = fmaxf(mx, sb[u * 64 + tid]);
            float s = 0.f;
#pragma unroll
            for (int u = 0; u < 16; ++u) { float e = __expf(sb[u * 64 + tid] - mx); sb[u * 64 + tid] = e; s += e; }
            float inv = 1.f / s;
#pragma unroll
            for (int u = 0; u < 16; ++u) sb[u * 64 + tid] *= inv;
        }
        __syncthreads();
        // ---- O = P @ V (fp32) -> xb16 (as bf16 Ob) ----
        {
            int o = tid & 127, r0p = (tid >> 7) * 8, hh = o >> 5;
            float accp[8] = {0, 0, 0, 0, 0, 0, 0, 0};
            for (int u = 0; u < 16; ++u) {
                float vv = Vf[u * 132 + o];
                const float* pp = sb + u * 64 + hh * 16 + r0p;
#pragma unroll
                for (int r = 0; r < 8; ++r) accp[r] += pp[r] * vv;
            }
#pragma unroll
            for (int r = 0; r < 8; ++r)
                xb16[(r0p + r) * 136 + o] = f2b(accp[r]);
        }
        __syncthreads();
        // ---- Wo via MFMA: 8 n-tiles, wave w does nt = 2w, 2w+1; accumulate into xs ----
        {
            bf16x8 af[4];
#pragma unroll
            for (int ks = 0; ks < 4; ++ks)
                af[ks] = *(const bf16x8*)(xb16 + mrow * 136 + ks * 32 + quad * 8);
            f32x4 acc[2];
            acc[0] = (f32x4){0.f, 0.f, 0.f, 0.f};
            acc[1] = (f32x4){0.f, 0.f, 0.f, 0.f};
            const unsigned short* Ws = Wl + 49152;
#pragma unroll
            for (int i = 0; i < 2; ++i) {
                int nt = w * 2 + i;
#pragma unroll
                for (int ks = 0; ks < 4; ++ks) {
                    bf16x8 bf = *(const bf16x8*)(Ws + (size_t)((nt * 4 + ks) * 64 + lane) * 8);
                    acc[i] = __builtin_amdgcn_mfma_f32_16x16x32_bf16(af[ks], bf, acc[i], 0, 0, 0);
                }
            }
#pragma unroll
            for (int i = 0; i < 2; ++i) {
                int col = (w * 2 + i) * 16 + mrow;
                float bb = bo[l * 128 + col];
#pragma unroll
                for (int r = 0; r < 4; ++r)
                    xs[(quad * 4 + r) * 128 + col] += acc[i][r] + bb;
            }
        }
        __syncthreads();
        ln256(xs, ln1s + l * 128, ln1b + l * 128);
        // ---- xs -> xb16 (post-LN1) ----
        {
            const float* xp = xs + crow * 128 + ccb;
            unsigned v[4];
#pragma unroll
            for (int j = 0; j < 4; ++j)
                v[j] = (unsigned)f2b(xp[2 * j]) | ((unsigned)f2b(xp[2 * j + 1]) << 16);
            *(uint4*)(xb16 + crow * 136 + ccb) = make_uint4(v[0], v[1], v[2], v[3]);
        }
        __syncthreads();
        // ---- FF1 via MFMA: 32 n-tiles, wave w does nt = 8w..8w+7; relu -> hid16 ----
        {
            bf16x8 af[4];
#pragma unroll
            for (int ks = 0; ks < 4; ++ks)
                af[ks] = *(const bf16x8*)(xb16 + mrow * 136 + ks * 32 + quad * 8);
            f32x4 acc[8];
#pragma unroll
            for (int i = 0; i < 8; ++i) acc[i] = (f32x4){0.f, 0.f, 0.f, 0.f};
            const unsigned short* Ws = Wl + 65536;
#pragma unroll
            for (int i = 0; i < 8; ++i) {
                int nt = w * 8 + i;
#pragma unroll
                for (int ks = 0; ks < 4; ++ks) {
                    bf16x8 bf = *(const bf16x8*)(Ws + (size_t)((nt * 4 + ks) * 64 + lane) * 8);
                    acc[i] = __builtin_amdgcn_mfma_f32_16x16x32_bf16(af[ks], bf, acc[i], 0, 0, 0);
                }
            }
#pragma unroll
            for (int i = 0; i < 8; ++i) {
                int col = (w * 8 + i) * 16 + mrow;
                float bb = bff1[l * 512 + col];
#pragma unroll
                for (int r = 0; r < 4; ++r) {
                    float v = fmaxf(acc[i][r] + bb, 0.f);
                    hid16[(quad * 4 + r) * 520 + col] = f2b(v);
                }
            }
        }
        __syncthreads();
        // ---- FF2 via MFMA: 8 n-tiles x 16 k-steps; accumulate into xs ----
        {
            f32x4 a0 = (f32x4){0.f, 0.f, 0.f, 0.f};
            f32x4 a1 = (f32x4){0.f, 0.f, 0.f, 0.f};
            const unsigned short* Ws = Wl + 131072;
            int nt0 = w * 2, nt1 = w * 2 + 1;
#pragma unroll
            for (int ks = 0; ks < 16; ++ks) {
                bf16x8 af = *(const bf16x8*)(hid16 + mrow * 520 + ks * 32 + quad * 8);
                bf16x8 b0 = *(const bf16x8*)(Ws + (size_t)((nt0 * 16 + ks) * 64 + lane) * 8);
                bf16x8 b1 = *(const bf16x8*)(Ws + (size_t)((nt1 * 16 + ks) * 64 + lane) * 8);
                a0 = __builtin_amdgcn_mfma_f32_16x16x32_bf16(af, b0, a0, 0, 0, 0);
                a1 = __builtin_amdgcn_mfma_f32_16x16x32_bf16(af, b1, a1, 0, 0, 0);
            }
            int col0 = nt0 * 16 + mrow, col1 = nt1 * 16 + mrow;
            float bb0 = bff2[l * 128 + col0], bb1 = bff2[l * 128 + col1];
#pragma unroll
            for (int r = 0; r < 4; ++r) {
                xs[(quad * 4 + r) * 128 + col0] += a0[r] + bb0;
                xs[(quad * 4 + r) * 128 + col1] += a1[r] + bb1;
            }
        }
        __syncthreads();
        ln256(xs, ln2s + l * 128, ln2b + l * 128);
    }
    for (int idx = tid; idx < 2048; idx += 256)
        out[(size_t)m * 2048 + idx] = xs[idx];
}

extern "C" void kernel_launch(void* const* d_in, const int* in_sizes, int n_in,
                              void* d_out, int out_size, void* d_ws, size_t ws_size,
                              hipStream_t stream) {
    (void)in_sizes; (void)n_in; (void)out_size; (void)ws_size;
    const int*   ego  = (const int*)d_in[0];
    const float* pos  = (const float*)d_in[1];
    const float* adj  = (const float*)d_in[2];
    const float* g1W  = (const float*)d_in[3];
    const float* g1as = (const float*)d_in[4];
    const float* g1ad = (const float*)d_in[5];
    const float* g1b  = (const float*)d_in[6];
    const float* gW   = (const float*)d_in[7];
    const float* gas  = (const float*)d_in[8];
    const float* gad  = (const float*)d_in[9];
    const float* gb   = (const float*)d_in[10];
    const float* Wqkv = (const float*)d_in[11];
    const float* bqkv = (const float*)d_in[12];
    const float* Wo   = (const float*)d_in[13];
    const float* bo   = (const float*)d_in[14];
    const float* l1s  = (const float*)d_in[15];
    const float* l1b  = (const float*)d_in[16];
    const float* l2s  = (const float*)d_in[17];
    const float* l2b  = (const float*)d_in[18];
    const float* Wff1 = (const float*)d_in[19];
    const float* bff1 = (const float*)d_in[20];
    const float* Wff2 = (const float*)d_in[21];
    const float* bff2 = (const float*)d_in[22];

    unsigned short* x0  = (unsigned short*)d_ws;       // 2,097,152 sh (4 MB)
    unsigned short* x1  = x0 + 2097152;                // 4 MB
    unsigned short* h16 = x1 + 2097152;                // 8,388,608 sh (16 MB)
    float* ssb = (float*)(h16 + 8388608);              // 65,536 f
    float* sdb = ssb + 65536;                          // 65,536 f
    float* mfl = sdb + 65536;                          // 16,384 f
    int*   cnt = (int*)(mfl + 16384);                  // 16,384 i
    int*   nbr = cnt + 16384;                          // 1,048,576 i
    unsigned short* Wb16 = (unsigned short*)(nbr + 1048576);  // 1,310,720 sh (~2.6 MB)
    unsigned short* Wg16 = Wb16 + 983040;              // GAT weight frags

    k_prep<<<640, 256, 0, stream>>>(Wqkv, Wo, Wff1, Wff2, gW, Wb16);
    k_init<<<64, 256, 0, stream>>>(ego, mfl, cnt);
    k_edges<<<256, 256, 0, stream>>>(adj, mfl, cnt, nbr);

    // GAT layer 1 (F=2), projection + ss/sd fused
    k_gat1<<<NROWS, 128, 0, stream>>>(pos, g1W, g1as, g1ad, h16, ssb, sdb);
    k_agg<<<NROWS, 128, 0, stream>>>(h16, ssb, sdb, cnt, nbr, mfl, g1b, x0);

    unsigned short* xin = x0; unsigned short* xout = x1;
    for (int L = 0; L < 5; ++L) {
        k_gat_h<<<1024, 256, 0, stream>>>(xin, Wg16 + (size_t)L * 65536,
                                          gas + L * 512, gad + L * 512, h16, ssb, sdb);
        k_agg<<<NROWS, 128, 0, stream>>>(h16, ssb, sdb, cnt, nbr, mfl, gb + L * 128, xout);
        unsigned short* tmp = xin; xin = xout; xout = tmp;
    }

    k_tf<<<MM, 256, 0, stream>>>(xin, Wb16, bqkv, bo, l1s, l1b, l2s, l2b,
                                 bff1, bff2, (float*)d_out);
}

// Round 9
// 800.445 us; speedup vs baseline: 2.5367x; 1.0273x over previous
//
#include <hip/hip_runtime.h>
#include <hip/hip_bf16.h>

// Problem constants
#define TT 16
#define MM 1024
#define HDIM 128
#define NHEADS 4
#define NROWS (TT*MM)          // 16384
#define MAXDEG 64

typedef __bf16 bf16x8 __attribute__((ext_vector_type(8)));
typedef float f32x4 __attribute__((ext_vector_type(4)));

__device__ __forceinline__ unsigned short f2b(float x) {   // fp32 -> bf16 RNE
    unsigned u = __float_as_uint(x);
    u += 0x7fff + ((u >> 16) & 1);
    return (unsigned short)(u >> 16);
}
__device__ __forceinline__ float bu2f(unsigned short u) {
    return __uint_as_float(((unsigned)u) << 16);
}

// ---------------- mask + neighbor-list build ----------------
__global__ __launch_bounds__(256) void k_init(const int* __restrict__ ego,
                                              float* __restrict__ mfl,
                                              int* __restrict__ cnt) {
    int idx = blockIdx.x * 256 + threadIdx.x;   // < 16384
    int t = idx >> 10, i = idx & 1023;
    int b = i >> 8, n = i & 255;
    mfl[idx] = ego[b * (TT * 256) + t * 256 + n] ? 1.f : 0.f;
    cnt[idx] = 0;
}

__global__ __launch_bounds__(256) void k_edges(const float* __restrict__ adj,
                                               const float* __restrict__ mfl,
                                               int* __restrict__ cnt,
                                               int* __restrict__ nbr) {
    int bid = blockIdx.x;            // 256 blocks: t(16) x jc(4) x ic(4)
    int t = bid >> 4, jc = (bid >> 2) & 3, ic = bid & 3;
    int tid = threadIdx.x;
    int i = ic * 256 + tid;
    int row = t * MM + i;
    __shared__ float ms[256];
    int j0 = jc * 256;
    ms[tid] = mfl[t * MM + j0 + tid];
    __syncthreads();
    float mi = mfl[row];
    if (mi == 0.f) return;
    const float* at = adj + (size_t)t * MM * MM;
    for (int jj = 0; jj < 256; ++jj) {
        int j = j0 + jj;
        bool e;
        if (j == i) e = true;                                   // self-loop
        else e = (at[(size_t)j * MM + i] != 0.f) && (ms[jj] != 0.f);
        if (e) {
            int pos = atomicAdd(&cnt[row], 1);
            if (pos < MAXDEG) nbr[(size_t)row * MAXDEG + pos] = j;
        }
    }
}

// ---------------- weight prep: fp32 -> bf16 MFMA B-fragment order ----------------
__global__ __launch_bounds__(256) void k_prep(const float* __restrict__ Wqkv,
                                              const float* __restrict__ Wo,
                                              const float* __restrict__ Wff1,
                                              const float* __restrict__ Wff2,
                                              const float* __restrict__ gW,
                                              unsigned short* __restrict__ Wb) {
    int o = blockIdx.x * 256 + threadIdx.x;     // frag-unit (8 elems) index, < 163840
    const float* src; int cs;
    if (o < 122880) {
        int l = o / 24576, r = o % 24576;
        if (r < 6144) {                 // QKV
            int nt = r >> 8, rem = r & 255, ks = rem >> 6, lane = rem & 63;
            int mt = nt >> 3, cc = nt & 7;
            int k = ks * 32 + ((lane >> 4) << 3), c = cc * 16 + (lane & 15);
            src = Wqkv + ((size_t)(l * 3 + mt) * 128 + k) * 128 + c; cs = 128;
        } else if (r < 8192) {          // Wo
            int u = r - 6144, nt = u >> 8, rem = u & 255, ks = rem >> 6, lane = rem & 63;
            int k = ks * 32 + ((lane >> 4) << 3), c = nt * 16 + (lane & 15);
            src = Wo + (size_t)l * 16384 + (size_t)k * 128 + c; cs = 128;
        } else if (r < 16384) {         // FF1
            int u = r - 8192, nt = u >> 8, rem = u & 255, ks = rem >> 6, lane = rem & 63;
            int k = ks * 32 + ((lane >> 4) << 3), c = nt * 16 + (lane & 15);
            src = Wff1 + (size_t)l * 65536 + (size_t)k * 512 + c; cs = 512;
        } else {                        // FF2
            int u = r - 16384, nt = u >> 10, rem = u & 1023, ks = rem >> 6, lane = rem & 63;
            int k = ks * 32 + ((lane >> 4) << 3), c = nt * 16 + (lane & 15);
            src = Wff2 + (size_t)l * 65536 + (size_t)k * 128 + c; cs = 128;
        }
    } else {                            // GAT gW
        int u = o - 122880;
        int l = u >> 13, rr = u & 8191;
        int nt = rr >> 8, rem = rr & 255, ks = rem >> 6, lane = rem & 63;
        int k = ks * 32 + ((lane >> 4) << 3), c = nt * 16 + (lane & 15);
        src = gW + (size_t)l * 65536 + (size_t)k * 512 + c; cs = 512;
    }
    unsigned v[4];
#pragma unroll
    for (int j = 0; j < 4; ++j)
        v[j] = (unsigned)f2b(src[(2 * j) * (size_t)cs]) |
               ((unsigned)f2b(src[(2 * j + 1) * (size_t)cs]) << 16);
    *(uint4*)(Wb + (size_t)o * 8) = make_uint4(v[0], v[1], v[2], v[3]);
}

// ---------------- GAT layer 1: projection (F=2) + fused ss/sd; h -> bf16 ----------------
__global__ __launch_bounds__(128) void k_gat1(const float* __restrict__ x,
                                              const float* __restrict__ W,
                                              const float* __restrict__ asrc,
                                              const float* __restrict__ adst,
                                              unsigned short* __restrict__ h16,
                                              float* __restrict__ ss,
                                              float* __restrict__ sd) {
    int bid = blockIdx.x;
    int row = ((bid & 7) << 11) + (bid >> 3);   // XCD-locality swizzle
    int tid = threadIdx.x;
    float x0 = x[row * 2], x1 = x[row * 2 + 1];
    float s4[4], d4[4];
#pragma unroll
    for (int hh = 0; hh < 4; ++hh) {
        int o = hh * 128 + tid;
        float v = x0 * W[o] + x1 * W[512 + o];
        h16[(size_t)row * 512 + o] = f2b(v);
        s4[hh] = v * asrc[o];
        d4[hh] = v * adst[o];
    }
#pragma unroll
    for (int hh = 0; hh < 4; ++hh)
        for (int off = 32; off; off >>= 1) {
            s4[hh] += __shfl_down(s4[hh], off, 64);
            d4[hh] += __shfl_down(d4[hh], off, 64);
        }
    __shared__ float red[2][2][4];
    if ((tid & 63) == 0) {
        int w = tid >> 6;
#pragma unroll
        for (int hh = 0; hh < 4; ++hh) { red[w][0][hh] = s4[hh]; red[w][1][hh] = d4[hh]; }
    }
    __syncthreads();
    if (tid < 4) ss[row * 4 + tid] = red[0][0][tid] + red[1][0][tid];
    else if (tid < 8) sd[row * 4 + tid - 4] = red[0][1][tid - 4] + red[1][1][tid - 4];
}

// ---------------- GAT layers 2-6: MFMA projection + fused ss/sd ----------------
__global__ __launch_bounds__(256) void k_gat_h(const unsigned short* __restrict__ x16,
                                               const unsigned short* __restrict__ Wg,
                                               const float* __restrict__ asrc,
                                               const float* __restrict__ adst,
                                               unsigned short* __restrict__ h16,
                                               float* __restrict__ ss,
                                               float* __restrict__ sd) {
    __shared__ __align__(16) unsigned short xb[16 * 136];
    int bid = blockIdx.x;
    int row0 = (((bid & 7) << 7) + (bid >> 3)) * 16;   // band swizzle, XCD mapping
    int tid = threadIdx.x;
    {
        int rr = tid >> 4, cc = (tid & 15) * 8;
        *(uint4*)(xb + rr * 136 + cc) = *(const uint4*)(x16 + (size_t)(row0 + rr) * 128 + cc);
    }
    __syncthreads();
    const int lane = tid & 63, w = tid >> 6;
    const int mrow = lane & 15, quad = lane >> 4;
    bf16x8 af[4];
#pragma unroll
    for (int ks = 0; ks < 4; ++ks)
        af[ks] = *(const bf16x8*)(xb + mrow * 136 + ks * 32 + quad * 8);
    f32x4 acc[8];
#pragma unroll
    for (int i = 0; i < 8; ++i) acc[i] = (f32x4){0.f, 0.f, 0.f, 0.f};
#pragma unroll
    for (int ib = 0; ib < 4; ++ib) {   // batches of 2 nt x 4 ks -> 8 loads in flight
        bf16x8 wb[8];
#pragma unroll
        for (int u = 0; u < 2; ++u) {
            int nt = w * 8 + ib * 2 + u;
#pragma unroll
            for (int ks = 0; ks < 4; ++ks)
                wb[u * 4 + ks] = *(const bf16x8*)(Wg + (size_t)((nt * 4 + ks) * 64 + lane) * 8);
        }
#pragma unroll
        for (int u = 0; u < 2; ++u)
#pragma unroll
            for (int ks = 0; ks < 4; ++ks)
                acc[ib * 2 + u] = __builtin_amdgcn_mfma_f32_16x16x32_bf16(af[ks], wb[u * 4 + ks], acc[ib * 2 + u], 0, 0, 0);
    }
    float ps[4] = {0, 0, 0, 0}, pd[4] = {0, 0, 0, 0};
#pragma unroll
    for (int i = 0; i < 8; ++i) {
        int nt = w * 8 + i, col = nt * 16 + mrow;
        float as_ = asrc[col], ad_ = adst[col];
#pragma unroll
        for (int r = 0; r < 4; ++r) {
            float v = acc[i][r];
            h16[(size_t)(row0 + quad * 4 + r) * 512 + col] = f2b(v);
            ps[r] += v * as_; pd[r] += v * ad_;
        }
    }
#pragma unroll
    for (int off = 1; off < 16; off <<= 1)
#pragma unroll
        for (int r = 0; r < 4; ++r) {
            ps[r] += __shfl_xor(ps[r], off, 64);
            pd[r] += __shfl_xor(pd[r], off, 64);
        }
    if (mrow == 0) {
#pragma unroll
        for (int r = 0; r < 4; ++r) {
            int row = row0 + quad * 4 + r;
            ss[row * 4 + w] = ps[r];
            sd[row * 4 + w] = pd[r];
        }
    }
}

// ---------------- GAT aggregation: vectorized bf16 gather + parallel softmax -------------
__global__ __launch_bounds__(128) void k_agg(const unsigned short* __restrict__ h16,
                                             const float* __restrict__ ss,
                                             const float* __restrict__ sd,
                                             const int* __restrict__ cnt,
                                             const int* __restrict__ nbr,
                                             const float* __restrict__ mfl,
                                             const float* __restrict__ bias,
                                             unsigned short* __restrict__ xo16) {
    int bid = blockIdx.x;
    int row = ((bid & 7) << 11) + (bid >> 3);   // same-t rows colocate per XCD
    int tid = threadIdx.x;
    int t = row >> 10;
    if (mfl[row] == 0.f) { xo16[(size_t)row * 128 + tid] = 0; return; }
    int c = cnt[row]; if (c > MAXDEG) c = MAXDEG;
    __shared__ int nb[MAXDEG];
    __shared__ float al[MAXDEG][4];
    __shared__ __align__(16) float part[512];
    if (tid < c) nb[tid] = nbr[(size_t)row * MAXDEG + tid];
    __syncthreads();
    for (int idx = tid; idx < c * 4; idx += 128) {
        int n = idx >> 2, hh = idx & 3, j = nb[n];
        float lg = sd[row * 4 + hh] + ss[(t * MM + j) * 4 + hh];
        al[n][hh] = lg > 0.f ? lg : 0.2f * lg;   // leaky_relu 0.2
    }
    __syncthreads();
    // parallel segment softmax: 32 lanes per head
    {
        int hh = tid >> 5, n0 = tid & 31;
        float v1 = (n0 < c) ? al[n0][hh] : -1e30f;
        float v2 = (n0 + 32 < c) ? al[n0 + 32][hh] : -1e30f;
        float mx = fmaxf(v1, v2);
#pragma unroll
        for (int off = 16; off; off >>= 1) mx = fmaxf(mx, __shfl_xor(mx, off, 32));
        float e1 = (n0 < c) ? __expf(v1 - mx) : 0.f;
        float e2 = (n0 + 32 < c) ? __expf(v2 - mx) : 0.f;
        float s = e1 + e2;
#pragma unroll
        for (int off = 16; off; off >>= 1) s += __shfl_xor(s, off, 32);
        float inv = 1.f / s;
        if (n0 < c) al[n0][hh] = e1 * inv;
        if (n0 + 32 < c) al[n0 + 32][hh] = e2 * inv;
    }
    __syncthreads();
    // gather: thread owns 4 consecutive cols (one uint2 = 4 bf16 per neighbor)
    float a0 = 0.f, a1 = 0.f, a2 = 0.f, a3 = 0.f;
    int hh2 = tid >> 5;
    const unsigned short* hbase = h16 + (size_t)t * MM * 512 + tid * 4;
    for (int n = 0; n < c; ++n) {
        int j = nb[n];
        uint2 v = *(const uint2*)(hbase + (size_t)j * 512);
        float w = al[n][hh2];
        a0 += w * bu2f((unsigned short)(v.x & 0xffff));
        a1 += w * bu2f((unsigned short)(v.x >> 16));
        a2 += w * bu2f((unsigned short)(v.y & 0xffff));
        a3 += w * bu2f((unsigned short)(v.y >> 16));
    }
    *(float4*)(part + tid * 4) = make_float4(a0, a1, a2, a3);
    __syncthreads();
    float v = 0.25f * (part[tid] + part[128 + tid] + part[256 + tid] + part[384 + tid]) + bias[tid];
    xo16[(size_t)row * 128 + tid] = f2b(fmaxf(v, 0.f));
}

// ---------------- in-place LayerNorm, 16 rows x 128, 256 threads ----------------
__device__ __forceinline__ void ln256(float* xs, const float* s, const float* b) {
    int tid = threadIdx.x, row = tid >> 4, lane = tid & 15;
    float* xr = xs + row * 128;
    float sum = 0.f;
#pragma unroll
    for (int k2 = 0; k2 < 8; ++k2) sum += xr[lane + 16 * k2];
#pragma unroll
    for (int off = 8; off; off >>= 1) sum += __shfl_xor(sum, off, 16);
    float mean = sum * (1.f / 128.f);
    float vs = 0.f;
#pragma unroll
    for (int k2 = 0; k2 < 8; ++k2) { float d = xr[lane + 16 * k2] - mean; vs += d * d; }
#pragma unroll
    for (int off = 8; off; off >>= 1) vs += __shfl_xor(vs, off, 16);
    float rstd = rsqrtf(vs * (1.f / 128.f) + 1e-5f);
#pragma unroll
    for (int k2 = 0; k2 < 8; ++k2) {
        int d = lane + 16 * k2;
        float v = (xr[d] - mean) * rstd;
        xr[d] = v * s[d] + b[d];
    }
    __syncthreads();
}

// ---------------- 5-layer transformer: MFMA bf16, batched weight loads ----------------
// LDS = 2048(xs) + 2112(Qf) + 2112(Kf) + 1024(sb) + 1088(Vf16) + 1088(xb16) = 9472 fl
// = 37888 B -> 4 blocks/CU, grid 1024 fully resident in ONE pass.
__global__ __launch_bounds__(256, 4) void k_tf(const unsigned short* __restrict__ xg,
        const unsigned short* __restrict__ Wb,
        const float* __restrict__ bqkv, const float* __restrict__ bo,
        const float* __restrict__ ln1s, const float* __restrict__ ln1b,
        const float* __restrict__ ln2s, const float* __restrict__ ln2b,
        const float* __restrict__ bff1, const float* __restrict__ bff2,
        float* __restrict__ out) {
    __shared__ __align__(16) float smem[9472];
    float* xs = smem;                  // [16][128] residual fp32
    float* Qf = smem + 2048;           // [16][132] fp32
    float* Kf = smem + 4160;           // [16][132] fp32
    float* sb = smem + 6272;           // [16tk][64] transposed scores
    unsigned short* Vf16  = (unsigned short*)(smem + 7296); // [16][136] bf16
    unsigned short* xb16  = (unsigned short*)(smem + 8384); // [16][136] bf16 A-operand
    unsigned short* hid16 = (unsigned short*)(smem + 2048); // [16][520] bf16, overlays Qf+Kf
    const int m = blockIdx.x, tid = threadIdx.x;
    const int lane = tid & 63, w = tid >> 6;
    const int mrow = lane & 15, quad = lane >> 4;

    // load + sinusoidal PE
    for (int idx = tid; idx < 2048; idx += 256) {
        int t = idx >> 7, d = idx & 127, jj = d >> 1;
        float arg = (float)t * expf(-(float)(2 * jj) * (9.210340371976184f / 128.f));
        float pe = (d & 1) ? cosf(arg) : sinf(arg);
        xs[idx] = bu2f(xg[(size_t)t * (MM * HDIM) + (size_t)m * HDIM + d]) + pe;
    }
    __syncthreads();

    const int crow = tid >> 4, ccb = (tid & 15) * 8;   // xs->xb16 conversion slots
    for (int l = 0; l < 5; ++l) {
        const unsigned short* Wl = Wb + (size_t)l * 196608;
        // ---- xs -> xb16 ----
        {
            const float* xp = xs + crow * 128 + ccb;
            unsigned v[4];
#pragma unroll
            for (int j = 0; j < 4; ++j)
                v[j] = (unsigned)f2b(xp[2 * j]) | ((unsigned)f2b(xp[2 * j + 1]) << 16);
            *(uint4*)(xb16 + crow * 136 + ccb) = make_uint4(v[0], v[1], v[2], v[3]);
        }
        __syncthreads();
        // ---- QKV via MFMA: wave w does nt = 6w..6w+5, batched loads ----
        {
            bf16x8 af[4];
#pragma unroll
            for (int ks = 0; ks < 4; ++ks)
                af[ks] = *(const bf16x8*)(xb16 + mrow * 136 + ks * 32 + quad * 8);
            f32x4 acc[6];
#pragma unroll
            for (int i = 0; i < 6; ++i) acc[i] = (f32x4){0.f, 0.f, 0.f, 0.f};
#pragma unroll
            for (int ib = 0; ib < 3; ++ib) {
                bf16x8 wb[8];
#pragma unroll
                for (int u = 0; u < 2; ++u) {
                    int nt = w * 6 + ib * 2 + u;
                    const unsigned short* bp = Wl + (size_t)(nt * 4) * 512 + lane * 8;
#pragma unroll
                    for (int ks = 0; ks < 4; ++ks)
                        wb[u * 4 + ks] = *(const bf16x8*)(bp + ks * 512);
                }
#pragma unroll
                for (int u = 0; u < 2; ++u)
#pragma unroll
                    for (int ks = 0; ks < 4; ++ks)
                        acc[ib * 2 + u] = __builtin_amdgcn_mfma_f32_16x16x32_bf16(af[ks], wb[u * 4 + ks], acc[ib * 2 + u], 0, 0, 0);
            }
#pragma unroll
            for (int i = 0; i < 6; ++i) {
                int nt = w * 6 + i, mt = nt >> 3, cc = nt & 7;
                int col = cc * 16 + mrow;
                float bb = bqkv[l * 384 + mt * 128 + col];
                if (mt == 2) {
#pragma unroll
                    for (int r = 0; r < 4; ++r)
                        Vf16[(quad * 4 + r) * 136 + col] = f2b(acc[i][r] + bb);
                } else {
                    float* dst = (mt == 0) ? Qf : Kf;
#pragma unroll
                    for (int r = 0; r < 4; ++r)
                        dst[(quad * 4 + r) * 132 + col] = acc[i][r] + bb;
                }
            }
        }
        __syncthreads();
        // ---- scores (fp32 VALU): thread = (hh, tq, tk0..tk0+3) ----
        {
            int hh = tid >> 6, tq = (tid >> 2) & 15, tk0 = (tid & 3) * 4;
            const float* qp = Qf + tq * 132 + hh * 32;
            float a[4] = {0.f, 0.f, 0.f, 0.f};
#pragma unroll
            for (int d = 0; d < 8; ++d) {
                float4 q4 = *(const float4*)(qp + 4 * d);
#pragma unroll
                for (int j = 0; j < 4; ++j) {
                    float4 k4 = *(const float4*)(Kf + (tk0 + j) * 132 + hh * 32 + 4 * d);
                    a[j] += q4.x * k4.x + q4.y * k4.y + q4.z * k4.z + q4.w * k4.w;
                }
            }
#pragma unroll
            for (int j = 0; j < 4; ++j)
                sb[(tk0 + j) * 64 + hh * 16 + tq] = a[j] * 0.17677669529663687f;
        }
        __syncthreads();
        if (tid < 64) {   // softmax per (hh,tq) column
            float mx = -1e30f;
#pragma unroll
            for (int u = 0; u < 16; ++u) mx = fmaxf(mx, sb[u * 64 + tid]);
            float s = 0.f;
#pragma unroll
            for (int u = 0; u < 16; ++u) { float e = __expf(sb[u * 64 + tid] - mx); sb[u * 64 + tid] = e; s += e; }
            float inv = 1.f / s;
#pragma unroll
            for (int u = 0; u < 16; ++u) sb[u * 64 + tid] *= inv;
        }
        __syncthreads();
        // ---- O = P @ V (fp32, bf16 V) -> xb16 ----
        {
            int o = tid & 127, r0p = (tid >> 7) * 8, hh = o >> 5;
            float accp[8] = {0, 0, 0, 0, 0, 0, 0, 0};
            for (int u = 0; u < 16; ++u) {
                float vv = bu2f(Vf16[u * 136 + o]);
                const float* pp = sb + u * 64 + hh * 16 + r0p;
#pragma unroll
                for (int r = 0; r < 8; ++r) accp[r] += pp[r] * vv;
            }
#pragma unroll
            for (int r = 0; r < 8; ++r)
                xb16[(r0p + r) * 136 + o] = f2b(accp[r]);
        }
        __syncthreads();
        // ---- Wo via MFMA: wave w does nt = 2w, 2w+1; one batch of 8 loads ----
        {
            bf16x8 af[4];
#pragma unroll
            for (int ks = 0; ks < 4; ++ks)
                af[ks] = *(const bf16x8*)(xb16 + mrow * 136 + ks * 32 + quad * 8);
            const unsigned short* Ws = Wl + 49152;
            bf16x8 wb[8];
#pragma unroll
            for (int u = 0; u < 2; ++u) {
                int nt = w * 2 + u;
#pragma unroll
                for (int ks = 0; ks < 4; ++ks)
                    wb[u * 4 + ks] = *(const bf16x8*)(Ws + (size_t)((nt * 4 + ks) * 64 + lane) * 8);
            }
            f32x4 acc[2];
            acc[0] = (f32x4){0.f, 0.f, 0.f, 0.f};
            acc[1] = (f32x4){0.f, 0.f, 0.f, 0.f};
#pragma unroll
            for (int u = 0; u < 2; ++u)
#pragma unroll
                for (int ks = 0; ks < 4; ++ks)
                    acc[u] = __builtin_amdgcn_mfma_f32_16x16x32_bf16(af[ks], wb[u * 4 + ks], acc[u], 0, 0, 0);
#pragma unroll
            for (int u = 0; u < 2; ++u) {
                int col = (w * 2 + u) * 16 + mrow;
                float bb = bo[l * 128 + col];
#pragma unroll
                for (int r = 0; r < 4; ++r)
                    xs[(quad * 4 + r) * 128 + col] += acc[u][r] + bb;
            }
        }
        __syncthreads();
        ln256(xs, ln1s + l * 128, ln1b + l * 128);
        // ---- xs -> xb16 (post-LN1) ----
        {
            const float* xp = xs + crow * 128 + ccb;
            unsigned v[4];
#pragma unroll
            for (int j = 0; j < 4; ++j)
                v[j] = (unsigned)f2b(xp[2 * j]) | ((unsigned)f2b(xp[2 * j + 1]) << 16);
            *(uint4*)(xb16 + crow * 136 + ccb) = make_uint4(v[0], v[1], v[2], v[3]);
        }
        __syncthreads();
        // ---- FF1 via MFMA: wave w does nt = 8w..8w+7, batched; relu -> hid16 ----
        {
            bf16x8 af[4];
#pragma unroll
            for (int ks = 0; ks < 4; ++ks)
                af[ks] = *(const bf16x8*)(xb16 + mrow * 136 + ks * 32 + quad * 8);
            f32x4 acc[8];
#pragma unroll
            for (int i = 0; i < 8; ++i) acc[i] = (f32x4){0.f, 0.f, 0.f, 0.f};
            const unsigned short* Ws = Wl + 65536;
#pragma unroll
            for (int ib = 0; ib < 4; ++ib) {
                bf16x8 wb[8];
#pragma unroll
                for (int u = 0; u < 2; ++u) {
                    int nt = w * 8 + ib * 2 + u;
#pragma unroll
                    for (int ks = 0; ks < 4; ++ks)
                        wb[u * 4 + ks] = *(const bf16x8*)(Ws + (size_t)((nt * 4 + ks) * 64 + lane) * 8);
                }
#pragma unroll
                for (int u = 0; u < 2; ++u)
#pragma unroll
                    for (int ks = 0; ks < 4; ++ks)
                        acc[ib * 2 + u] = __builtin_amdgcn_mfma_f32_16x16x32_bf16(af[ks], wb[u * 4 + ks], acc[ib * 2 + u], 0, 0, 0);
            }
#pragma unroll
            for (int i = 0; i < 8; ++i) {
                int col = (w * 8 + i) * 16 + mrow;
                float bb = bff1[l * 512 + col];
#pragma unroll
                for (int r = 0; r < 4; ++r) {
                    float v = fmaxf(acc[i][r] + bb, 0.f);
                    hid16[(quad * 4 + r) * 520 + col] = f2b(v);
                }
            }
        }
        __syncthreads();
        // ---- FF2 via MFMA: 2 nt x 16 ks per wave, batched 4 ks at a time ----
        {
            f32x4 a0 = (f32x4){0.f, 0.f, 0.f, 0.f};
            f32x4 a1 = (f32x4){0.f, 0.f, 0.f, 0.f};
            const unsigned short* Ws = Wl + 131072;
            int nt0 = w * 2, nt1 = w * 2 + 1;
#pragma unroll
            for (int kb = 0; kb < 4; ++kb) {
                bf16x8 afb[4], w0[4], w1[4];
#pragma unroll
                for (int kk = 0; kk < 4; ++kk) {
                    int ks = kb * 4 + kk;
                    afb[kk] = *(const bf16x8*)(hid16 + mrow * 520 + ks * 32 + quad * 8);
                    w0[kk] = *(const bf16x8*)(Ws + (size_t)((nt0 * 16 + ks) * 64 + lane) * 8);
                    w1[kk] = *(const bf16x8*)(Ws + (size_t)((nt1 * 16 + ks) * 64 + lane) * 8);
                }
#pragma unroll
                for (int kk = 0; kk < 4; ++kk) {
                    a0 = __builtin_amdgcn_mfma_f32_16x16x32_bf16(afb[kk], w0[kk], a0, 0, 0, 0);
                    a1 = __builtin_amdgcn_mfma_f32_16x16x32_bf16(afb[kk], w1[kk], a1, 0, 0, 0);
                }
            }
            int col0 = nt0 * 16 + mrow, col1 = nt1 * 16 + mrow;
            float bb0 = bff2[l * 128 + col0], bb1 = bff2[l * 128 + col1];
#pragma unroll
            for (int r = 0; r < 4; ++r) {
                xs[(quad * 4 + r) * 128 + col0] += a0[r] + bb0;
                xs[(quad * 4 + r) * 128 + col1] += a1[r] + bb1;
            }
        }
        __syncthreads();
        ln256(xs, ln2s + l * 128, ln2b + l * 128);
    }
    for (int idx = tid; idx < 2048; idx += 256)
        out[(size_t)m * 2048 + idx] = xs[idx];
}

extern "C" void kernel_launch(void* const* d_in, const int* in_sizes, int n_in,
                              void* d_out, int out_size, void* d_ws, size_t ws_size,
                              hipStream_t stream) {
    (void)in_sizes; (void)n_in; (void)out_size; (void)ws_size;
    const int*   ego  = (const int*)d_in[0];
    const float* pos  = (const float*)d_in[1];
    const float* adj  = (const float*)d_in[2];
    const float* g1W  = (const float*)d_in[3];
    const float* g1as = (const float*)d_in[4];
    const float* g1ad = (const float*)d_in[5];
    const float* g1b  = (const float*)d_in[6];
    const float* gW   = (const float*)d_in[7];
    const float* gas  = (const float*)d_in[8];
    const float* gad  = (const float*)d_in[9];
    const float* gb   = (const float*)d_in[10];
    const float* Wqkv = (const float*)d_in[11];
    const float* bqkv = (const float*)d_in[12];
    const float* Wo   = (const float*)d_in[13];
    const float* bo   = (const float*)d_in[14];
    const float* l1s  = (const float*)d_in[15];
    const float* l1b  = (const float*)d_in[16];
    const float* l2s  = (const float*)d_in[17];
    const float* l2b  = (const float*)d_in[18];
    const float* Wff1 = (const float*)d_in[19];
    const float* bff1 = (const float*)d_in[20];
    const float* Wff2 = (const float*)d_in[21];
    const float* bff2 = (const float*)d_in[22];

    unsigned short* x0  = (unsigned short*)d_ws;       // 2,097,152 sh (4 MB)
    unsigned short* x1  = x0 + 2097152;                // 4 MB
    unsigned short* h16 = x1 + 2097152;                // 8,388,608 sh (16 MB)
    float* ssb = (float*)(h16 + 8388608);              // 65,536 f
    float* sdb = ssb + 65536;                          // 65,536 f
    float* mfl = sdb + 65536;                          // 16,384 f
    int*   cnt = (int*)(mfl + 16384);                  // 16,384 i
    int*   nbr = cnt + 16384;                          // 1,048,576 i
    unsigned short* Wb16 = (unsigned short*)(nbr + 1048576);  // 1,310,720 sh (~2.6 MB)
    unsigned short* Wg16 = Wb16 + 983040;              // GAT weight frags

    k_prep<<<640, 256, 0, stream>>>(Wqkv, Wo, Wff1, Wff2, gW, Wb16);
    k_init<<<64, 256, 0, stream>>>(ego, mfl, cnt);
    k_edges<<<256, 256, 0, stream>>>(adj, mfl, cnt, nbr);

    // GAT layer 1 (F=2), projection + ss/sd fused
    k_gat1<<<NROWS, 128, 0, stream>>>(pos, g1W, g1as, g1ad, h16, ssb, sdb);
    k_agg<<<NROWS, 128, 0, stream>>>(h16, ssb, sdb, cnt, nbr, mfl, g1b, x0);

    unsigned short* xin = x0; unsigned short* xout = x1;
    for (int L = 0; L < 5; ++L) {
        k_gat_h<<<1024, 256, 0, stream>>>(xin, Wg16 + (size_t)L * 65536,
                                          gas + L * 512, gad + L * 512, h16, ssb, sdb);
        k_agg<<<NROWS, 128, 0, stream>>>(h16, ssb, sdb, cnt, nbr, mfl, gb + L * 128, xout);
        unsigned short* tmp = xin; xin = xout; xout = tmp;
    }

    k_tf<<<MM, 256, 0, stream>>>(xin, Wb16, bqkv, bo, l1s, l1b, l2s, l2b,
                                 bff1, bff2, (float*)d_out);
}

// Round 10
// 693.915 us; speedup vs baseline: 2.9262x; 1.1535x over previous
//
#include <hip/hip_runtime.h>
#include <hip/hip_bf16.h>

// Problem constants
#define TT 16
#define MM 1024
#define HDIM 128
#define NHEADS 4
#define NROWS (TT*MM)          // 16384
#define MAXDEG 64

typedef __bf16 bf16x8 __attribute__((ext_vector_type(8)));
typedef float f32x4 __attribute__((ext_vector_type(4)));

__device__ __forceinline__ unsigned short f2b(float x) {   // fp32 -> bf16 RNE
    unsigned u = __float_as_uint(x);
    u += 0x7fff + ((u >> 16) & 1);
    return (unsigned short)(u >> 16);
}
__device__ __forceinline__ float bu2f(unsigned short u) {
    return __uint_as_float(((unsigned)u) << 16);
}

// ---------------- mask + neighbor-list build ----------------
__global__ __launch_bounds__(256) void k_init(const int* __restrict__ ego,
                                              float* __restrict__ mfl,
                                              int* __restrict__ cnt) {
    int idx = blockIdx.x * 256 + threadIdx.x;   // < 16384
    int t = idx >> 10, i = idx & 1023;
    int b = i >> 8, n = i & 255;
    mfl[idx] = ego[b * (TT * 256) + t * 256 + n] ? 1.f : 0.f;
    cnt[idx] = 0;
}

__global__ __launch_bounds__(256) void k_edges(const float* __restrict__ adj,
                                               const float* __restrict__ mfl,
                                               int* __restrict__ cnt,
                                               int* __restrict__ nbr) {
    int bid = blockIdx.x;            // 256 blocks: t(16) x jc(4) x ic(4)
    int t = bid >> 4, jc = (bid >> 2) & 3, ic = bid & 3;
    int tid = threadIdx.x;
    int i = ic * 256 + tid;
    int row = t * MM + i;
    __shared__ float ms[256];
    int j0 = jc * 256;
    ms[tid] = mfl[t * MM + j0 + tid];
    __syncthreads();
    float mi = mfl[row];
    if (mi == 0.f) return;
    const float* at = adj + (size_t)t * MM * MM;
    for (int jj = 0; jj < 256; ++jj) {
        int j = j0 + jj;
        bool e;
        if (j == i) e = true;                                   // self-loop
        else e = (at[(size_t)j * MM + i] != 0.f) && (ms[jj] != 0.f);
        if (e) {
            int pos = atomicAdd(&cnt[row], 1);
            if (pos < MAXDEG) nbr[(size_t)row * MAXDEG + pos] = j;
        }
    }
}

// ---------------- weight prep: fp32 -> bf16 MFMA B-fragment order ----------------
__global__ __launch_bounds__(256) void k_prep(const float* __restrict__ Wqkv,
                                              const float* __restrict__ Wo,
                                              const float* __restrict__ Wff1,
                                              const float* __restrict__ Wff2,
                                              const float* __restrict__ gW,
                                              unsigned short* __restrict__ Wb) {
    int o = blockIdx.x * 256 + threadIdx.x;     // frag-unit (8 elems) index, < 163840
    const float* src; int cs;
    if (o < 122880) {
        int l = o / 24576, r = o % 24576;
        if (r < 6144) {                 // QKV
            int nt = r >> 8, rem = r & 255, ks = rem >> 6, lane = rem & 63;
            int mt = nt >> 3, cc = nt & 7;
            int k = ks * 32 + ((lane >> 4) << 3), c = cc * 16 + (lane & 15);
            src = Wqkv + ((size_t)(l * 3 + mt) * 128 + k) * 128 + c; cs = 128;
        } else if (r < 8192) {          // Wo
            int u = r - 6144, nt = u >> 8, rem = u & 255, ks = rem >> 6, lane = rem & 63;
            int k = ks * 32 + ((lane >> 4) << 3), c = nt * 16 + (lane & 15);
            src = Wo + (size_t)l * 16384 + (size_t)k * 128 + c; cs = 128;
        } else if (r < 16384) {         // FF1
            int u = r - 8192, nt = u >> 8, rem = u & 255, ks = rem >> 6, lane = rem & 63;
            int k = ks * 32 + ((lane >> 4) << 3), c = nt * 16 + (lane & 15);
            src = Wff1 + (size_t)l * 65536 + (size_t)k * 512 + c; cs = 512;
        } else {                        // FF2
            int u = r - 16384, nt = u >> 10, rem = u & 1023, ks = rem >> 6, lane = rem & 63;
            int k = ks * 32 + ((lane >> 4) << 3), c = nt * 16 + (lane & 15);
            src = Wff2 + (size_t)l * 65536 + (size_t)k * 128 + c; cs = 128;
        }
    } else {                            // GAT gW
        int u = o - 122880;
        int l = u >> 13, rr = u & 8191;
        int nt = rr >> 8, rem = rr & 255, ks = rem >> 6, lane = rem & 63;
        int k = ks * 32 + ((lane >> 4) << 3), c = nt * 16 + (lane & 15);
        src = gW + (size_t)l * 65536 + (size_t)k * 512 + c; cs = 512;
    }
    unsigned v[4];
#pragma unroll
    for (int j = 0; j < 4; ++j)
        v[j] = (unsigned)f2b(src[(2 * j) * (size_t)cs]) |
               ((unsigned)f2b(src[(2 * j + 1) * (size_t)cs]) << 16);
    *(uint4*)(Wb + (size_t)o * 8) = make_uint4(v[0], v[1], v[2], v[3]);
}

// ---------------- GAT layer 1: projection (F=2) + fused ss/sd; h -> bf16 ----------------
__global__ __launch_bounds__(128) void k_gat1(const float* __restrict__ x,
                                              const float* __restrict__ W,
                                              const float* __restrict__ asrc,
                                              const float* __restrict__ adst,
                                              unsigned short* __restrict__ h16,
                                              float* __restrict__ ss,
                                              float* __restrict__ sd) {
    int bid = blockIdx.x;
    int row = ((bid & 7) << 11) + (bid >> 3);   // XCD-locality swizzle
    int tid = threadIdx.x;
    float x0 = x[row * 2], x1 = x[row * 2 + 1];
    float s4[4], d4[4];
#pragma unroll
    for (int hh = 0; hh < 4; ++hh) {
        int o = hh * 128 + tid;
        float v = x0 * W[o] + x1 * W[512 + o];
        h16[(size_t)row * 512 + o] = f2b(v);
        s4[hh] = v * asrc[o];
        d4[hh] = v * adst[o];
    }
#pragma unroll
    for (int hh = 0; hh < 4; ++hh)
        for (int off = 32; off; off >>= 1) {
            s4[hh] += __shfl_down(s4[hh], off, 64);
            d4[hh] += __shfl_down(d4[hh], off, 64);
        }
    __shared__ float red[2][2][4];
    if ((tid & 63) == 0) {
        int w = tid >> 6;
#pragma unroll
        for (int hh = 0; hh < 4; ++hh) { red[w][0][hh] = s4[hh]; red[w][1][hh] = d4[hh]; }
    }
    __syncthreads();
    if (tid < 4) ss[row * 4 + tid] = red[0][0][tid] + red[1][0][tid];
    else if (tid < 8) sd[row * 4 + tid - 4] = red[0][1][tid - 4] + red[1][1][tid - 4];
}

// ---------------- GAT layers 2-6: MFMA projection + fused ss/sd ----------------
__global__ __launch_bounds__(256) void k_gat_h(const unsigned short* __restrict__ x16,
                                               const unsigned short* __restrict__ Wg,
                                               const float* __restrict__ asrc,
                                               const float* __restrict__ adst,
                                               unsigned short* __restrict__ h16,
                                               float* __restrict__ ss,
                                               float* __restrict__ sd) {
    __shared__ __align__(16) unsigned short xb[16 * 136];
    int bid = blockIdx.x;
    int row0 = (((bid & 7) << 7) + (bid >> 3)) * 16;   // band swizzle, XCD mapping
    int tid = threadIdx.x;
    {
        int rr = tid >> 4, cc = (tid & 15) * 8;
        *(uint4*)(xb + rr * 136 + cc) = *(const uint4*)(x16 + (size_t)(row0 + rr) * 128 + cc);
    }
    __syncthreads();
    const int lane = tid & 63, w = tid >> 6;
    const int mrow = lane & 15, quad = lane >> 4;
    bf16x8 af[4];
#pragma unroll
    for (int ks = 0; ks < 4; ++ks)
        af[ks] = *(const bf16x8*)(xb + mrow * 136 + ks * 32 + quad * 8);
    f32x4 acc[8];
#pragma unroll
    for (int i = 0; i < 8; ++i) acc[i] = (f32x4){0.f, 0.f, 0.f, 0.f};
#pragma unroll
    for (int ib = 0; ib < 4; ++ib) {   // batches of 2 nt x 4 ks -> 8 loads in flight
        bf16x8 wb[8];
#pragma unroll
        for (int u = 0; u < 2; ++u) {
            int nt = w * 8 + ib * 2 + u;
#pragma unroll
            for (int ks = 0; ks < 4; ++ks)
                wb[u * 4 + ks] = *(const bf16x8*)(Wg + (size_t)((nt * 4 + ks) * 64 + lane) * 8);
        }
#pragma unroll
        for (int u = 0; u < 2; ++u)
#pragma unroll
            for (int ks = 0; ks < 4; ++ks)
                acc[ib * 2 + u] = __builtin_amdgcn_mfma_f32_16x16x32_bf16(af[ks], wb[u * 4 + ks], acc[ib * 2 + u], 0, 0, 0);
    }
    float ps[4] = {0, 0, 0, 0}, pd[4] = {0, 0, 0, 0};
#pragma unroll
    for (int i = 0; i < 8; ++i) {
        int nt = w * 8 + i, col = nt * 16 + mrow;
        float as_ = asrc[col], ad_ = adst[col];
#pragma unroll
        for (int r = 0; r < 4; ++r) {
            float v = acc[i][r];
            h16[(size_t)(row0 + quad * 4 + r) * 512 + col] = f2b(v);
            ps[r] += v * as_; pd[r] += v * ad_;
        }
    }
#pragma unroll
    for (int off = 1; off < 16; off <<= 1)
#pragma unroll
        for (int r = 0; r < 4; ++r) {
            ps[r] += __shfl_xor(ps[r], off, 64);
            pd[r] += __shfl_xor(pd[r], off, 64);
        }
    if (mrow == 0) {
#pragma unroll
        for (int r = 0; r < 4; ++r) {
            int row = row0 + quad * 4 + r;
            ss[row * 4 + w] = ps[r];
            sd[row * 4 + w] = pd[r];
        }
    }
}

// ---------------- GAT aggregation: vectorized bf16 gather + parallel softmax -------------
__global__ __launch_bounds__(128) void k_agg(const unsigned short* __restrict__ h16,
                                             const float* __restrict__ ss,
                                             const float* __restrict__ sd,
                                             const int* __restrict__ cnt,
                                             const int* __restrict__ nbr,
                                             const float* __restrict__ mfl,
                                             const float* __restrict__ bias,
                                             unsigned short* __restrict__ xo16) {
    int bid = blockIdx.x;
    int row = ((bid & 7) << 11) + (bid >> 3);   // same-t rows colocate per XCD
    int tid = threadIdx.x;
    int t = row >> 10;
    if (mfl[row] == 0.f) { xo16[(size_t)row * 128 + tid] = 0; return; }
    int c = cnt[row]; if (c > MAXDEG) c = MAXDEG;
    __shared__ int nb[MAXDEG];
    __shared__ float al[MAXDEG][4];
    __shared__ __align__(16) float part[512];
    if (tid < c) nb[tid] = nbr[(size_t)row * MAXDEG + tid];
    __syncthreads();
    for (int idx = tid; idx < c * 4; idx += 128) {
        int n = idx >> 2, hh = idx & 3, j = nb[n];
        float lg = sd[row * 4 + hh] + ss[(t * MM + j) * 4 + hh];
        al[n][hh] = lg > 0.f ? lg : 0.2f * lg;   // leaky_relu 0.2
    }
    __syncthreads();
    // parallel segment softmax: 32 lanes per head
    {
        int hh = tid >> 5, n0 = tid & 31;
        float v1 = (n0 < c) ? al[n0][hh] : -1e30f;
        float v2 = (n0 + 32 < c) ? al[n0 + 32][hh] : -1e30f;
        float mx = fmaxf(v1, v2);
#pragma unroll
        for (int off = 16; off; off >>= 1) mx = fmaxf(mx, __shfl_xor(mx, off, 32));
        float e1 = (n0 < c) ? __expf(v1 - mx) : 0.f;
        float e2 = (n0 + 32 < c) ? __expf(v2 - mx) : 0.f;
        float s = e1 + e2;
#pragma unroll
        for (int off = 16; off; off >>= 1) s += __shfl_xor(s, off, 32);
        float inv = 1.f / s;
        if (n0 < c) al[n0][hh] = e1 * inv;
        if (n0 + 32 < c) al[n0 + 32][hh] = e2 * inv;
    }
    __syncthreads();
    // gather: thread owns 4 consecutive cols (one uint2 = 4 bf16 per neighbor)
    float a0 = 0.f, a1 = 0.f, a2 = 0.f, a3 = 0.f;
    int hh2 = tid >> 5;
    const unsigned short* hbase = h16 + (size_t)t * MM * 512 + tid * 4;
    for (int n = 0; n < c; ++n) {
        int j = nb[n];
        uint2 v = *(const uint2*)(hbase + (size_t)j * 512);
        float w = al[n][hh2];
        a0 += w * bu2f((unsigned short)(v.x & 0xffff));
        a1 += w * bu2f((unsigned short)(v.x >> 16));
        a2 += w * bu2f((unsigned short)(v.y & 0xffff));
        a3 += w * bu2f((unsigned short)(v.y >> 16));
    }
    *(float4*)(part + tid * 4) = make_float4(a0, a1, a2, a3);
    __syncthreads();
    float v = 0.25f * (part[tid] + part[128 + tid] + part[256 + tid] + part[384 + tid]) + bias[tid];
    xo16[(size_t)row * 128 + tid] = f2b(fmaxf(v, 0.f));
}

// ---------------- in-place LayerNorm, 16 rows x 128, 256 threads ----------------
__device__ __forceinline__ void ln256(float* xs, const float* s, const float* b) {
    int tid = threadIdx.x, row = tid >> 4, lane = tid & 15;
    float* xr = xs + row * 128;
    float sum = 0.f;
#pragma unroll
    for (int k2 = 0; k2 < 8; ++k2) sum += xr[lane + 16 * k2];
#pragma unroll
    for (int off = 8; off; off >>= 1) sum += __shfl_xor(sum, off, 16);
    float mean = sum * (1.f / 128.f);
    float vs = 0.f;
#pragma unroll
    for (int k2 = 0; k2 < 8; ++k2) { float d = xr[lane + 16 * k2] - mean; vs += d * d; }
#pragma unroll
    for (int off = 8; off; off >>= 1) vs += __shfl_xor(vs, off, 16);
    float rstd = rsqrtf(vs * (1.f / 128.f) + 1e-5f);
#pragma unroll
    for (int k2 = 0; k2 < 8; ++k2) {
        int d = lane + 16 * k2;
        float v = (xr[d] - mean) * rstd;
        xr[d] = v * s[d] + b[d];
    }
    __syncthreads();
}

// ---------------- 5-layer transformer: 2 sequences/block, MFMA bf16, batched loads -------
// LDS = 4096(xs) + 4224(Qf) + 4224(Kf) + 2048(sb) + 2176(Vf16) + 2176(xb16) = 18944 fl
// = 75776 B -> 2 blocks/CU; grid 512 = ONE pass. Each weight load feeds 2 MFMAs.
__global__ __launch_bounds__(256, 2) void k_tf(const unsigned short* __restrict__ xg,
        const unsigned short* __restrict__ Wb,
        const float* __restrict__ bqkv, const float* __restrict__ bo,
        const float* __restrict__ ln1s, const float* __restrict__ ln1b,
        const float* __restrict__ ln2s, const float* __restrict__ ln2b,
        const float* __restrict__ bff1, const float* __restrict__ bff2,
        float* __restrict__ out) {
    __shared__ __align__(16) float smem[18944];
    float* xs = smem;                  // [2][16][128] residual fp32
    float* Qf = smem + 4096;           // [2][16][132] fp32
    float* Kf = smem + 8320;           // [2][16][132] fp32
    float* sb = smem + 12544;          // [2][16tk][64] transposed scores
    unsigned short* Vf16  = (unsigned short*)(smem + 14592); // [2][16][136] bf16
    unsigned short* xb16  = (unsigned short*)(smem + 16768); // [2][16][136] bf16 A-operand
    unsigned short* hid16 = (unsigned short*)(smem + 4096);  // [2][16][520] bf16, overlays Qf+Kf
    const int m = blockIdx.x, tid = threadIdx.x;
    const int lane = tid & 63, w = tid >> 6;
    const int mrow = lane & 15, quad = lane >> 4;

    // load + sinusoidal PE (2 seqs)
    for (int idx = tid; idx < 4096; idx += 256) {
        int seq = idx >> 11, t = (idx >> 7) & 15, d = idx & 127, jj = d >> 1;
        float arg = (float)t * expf(-(float)(2 * jj) * (9.210340371976184f / 128.f));
        float pe = (d & 1) ? cosf(arg) : sinf(arg);
        xs[idx] = bu2f(xg[(size_t)t * (MM * HDIM) + (size_t)(2 * m + seq) * HDIM + d]) + pe;
    }
    __syncthreads();

    const int crow = tid >> 4, ccb = (tid & 15) * 8;   // xs->xb16 conversion slots
    for (int l = 0; l < 5; ++l) {
        const unsigned short* Wl = Wb + (size_t)l * 196608;
        // ---- xs -> xb16 (both seqs) ----
#pragma unroll
        for (int s = 0; s < 2; ++s) {
            const float* xp = xs + s * 2048 + crow * 128 + ccb;
            unsigned v[4];
#pragma unroll
            for (int j = 0; j < 4; ++j)
                v[j] = (unsigned)f2b(xp[2 * j]) | ((unsigned)f2b(xp[2 * j + 1]) << 16);
            *(uint4*)(xb16 + s * 2176 + crow * 136 + ccb) = make_uint4(v[0], v[1], v[2], v[3]);
        }
        __syncthreads();
        // ---- QKV via MFMA: wave w does nt = 6w..6w+5, 2 seqs per weight load ----
        {
            bf16x8 af[2][4];
#pragma unroll
            for (int s = 0; s < 2; ++s)
#pragma unroll
                for (int ks = 0; ks < 4; ++ks)
                    af[s][ks] = *(const bf16x8*)(xb16 + s * 2176 + mrow * 136 + ks * 32 + quad * 8);
            f32x4 acc[2][6];
#pragma unroll
            for (int s = 0; s < 2; ++s)
#pragma unroll
                for (int i = 0; i < 6; ++i) acc[s][i] = (f32x4){0.f, 0.f, 0.f, 0.f};
#pragma unroll
            for (int ib = 0; ib < 3; ++ib) {
                bf16x8 wb[8];
#pragma unroll
                for (int u = 0; u < 2; ++u) {
                    int nt = w * 6 + ib * 2 + u;
                    const unsigned short* bp = Wl + (size_t)(nt * 4) * 512 + lane * 8;
#pragma unroll
                    for (int ks = 0; ks < 4; ++ks)
                        wb[u * 4 + ks] = *(const bf16x8*)(bp + ks * 512);
                }
#pragma unroll
                for (int u = 0; u < 2; ++u)
#pragma unroll
                    for (int ks = 0; ks < 4; ++ks)
#pragma unroll
                        for (int s = 0; s < 2; ++s)
                            acc[s][ib * 2 + u] = __builtin_amdgcn_mfma_f32_16x16x32_bf16(af[s][ks], wb[u * 4 + ks], acc[s][ib * 2 + u], 0, 0, 0);
            }
#pragma unroll
            for (int i = 0; i < 6; ++i) {
                int nt = w * 6 + i, mt = nt >> 3, cc = nt & 7;
                int col = cc * 16 + mrow;
                float bb = bqkv[l * 384 + mt * 128 + col];
#pragma unroll
                for (int s = 0; s < 2; ++s) {
                    if (mt == 2) {
#pragma unroll
                        for (int r = 0; r < 4; ++r)
                            Vf16[s * 2176 + (quad * 4 + r) * 136 + col] = f2b(acc[s][i][r] + bb);
                    } else {
                        float* dst = ((mt == 0) ? Qf : Kf) + s * 2112;
#pragma unroll
                        for (int r = 0; r < 4; ++r)
                            dst[(quad * 4 + r) * 132 + col] = acc[s][i][r] + bb;
                    }
                }
            }
        }
        __syncthreads();
        // ---- scores (fp32 VALU), both seqs ----
#pragma unroll
        for (int s = 0; s < 2; ++s) {
            int hh = tid >> 6, tq = (tid >> 2) & 15, tk0 = (tid & 3) * 4;
            const float* qp = Qf + s * 2112 + tq * 132 + hh * 32;
            float a[4] = {0.f, 0.f, 0.f, 0.f};
#pragma unroll
            for (int d = 0; d < 8; ++d) {
                float4 q4 = *(const float4*)(qp + 4 * d);
#pragma unroll
                for (int j = 0; j < 4; ++j) {
                    float4 k4 = *(const float4*)(Kf + s * 2112 + (tk0 + j) * 132 + hh * 32 + 4 * d);
                    a[j] += q4.x * k4.x + q4.y * k4.y + q4.z * k4.z + q4.w * k4.w;
                }
            }
#pragma unroll
            for (int j = 0; j < 4; ++j)
                sb[s * 1024 + (tk0 + j) * 64 + hh * 16 + tq] = a[j] * 0.17677669529663687f;
        }
        __syncthreads();
        if (tid < 128) {   // softmax per (seq,hh,tq) column
            int s = tid >> 6, col = tid & 63;
            float* sp = sb + s * 1024;
            float mx = -1e30f;
#pragma unroll
            for (int u = 0; u < 16; ++u) mx = fmaxf(mx, sp[u * 64 + col]);
            float sm = 0.f;
#pragma unroll
            for (int u = 0; u < 16; ++u) { float e = __expf(sp[u * 64 + col] - mx); sp[u * 64 + col] = e; sm += e; }
            float inv = 1.f / sm;
#pragma unroll
            for (int u = 0; u < 16; ++u) sp[u * 64 + col] *= inv;
        }
        __syncthreads();
        // ---- O = P @ V (fp32, bf16 V) -> xb16, both seqs ----
#pragma unroll
        for (int s = 0; s < 2; ++s) {
            int o = tid & 127, r0p = (tid >> 7) * 8, hh = o >> 5;
            float accp[8] = {0, 0, 0, 0, 0, 0, 0, 0};
            for (int u = 0; u < 16; ++u) {
                float vv = bu2f(Vf16[s * 2176 + u * 136 + o]);
                const float* pp = sb + s * 1024 + u * 64 + hh * 16 + r0p;
#pragma unroll
                for (int r = 0; r < 8; ++r) accp[r] += pp[r] * vv;
            }
#pragma unroll
            for (int r = 0; r < 8; ++r)
                xb16[s * 2176 + (r0p + r) * 136 + o] = f2b(accp[r]);
        }
        __syncthreads();
        // ---- Wo via MFMA: wave w does nt = 2w, 2w+1 ----
        {
            bf16x8 af[2][4];
#pragma unroll
            for (int s = 0; s < 2; ++s)
#pragma unroll
                for (int ks = 0; ks < 4; ++ks)
                    af[s][ks] = *(const bf16x8*)(xb16 + s * 2176 + mrow * 136 + ks * 32 + quad * 8);
            const unsigned short* Ws = Wl + 49152;
            bf16x8 wb[8];
#pragma unroll
            for (int u = 0; u < 2; ++u) {
                int nt = w * 2 + u;
#pragma unroll
                for (int ks = 0; ks < 4; ++ks)
                    wb[u * 4 + ks] = *(const bf16x8*)(Ws + (size_t)((nt * 4 + ks) * 64 + lane) * 8);
            }
            f32x4 acc[2][2];
#pragma unroll
            for (int s = 0; s < 2; ++s) { acc[s][0] = (f32x4){0,0,0,0}; acc[s][1] = (f32x4){0,0,0,0}; }
#pragma unroll
            for (int u = 0; u < 2; ++u)
#pragma unroll
                for (int ks = 0; ks < 4; ++ks)
#pragma unroll
                    for (int s = 0; s < 2; ++s)
                        acc[s][u] = __builtin_amdgcn_mfma_f32_16x16x32_bf16(af[s][ks], wb[u * 4 + ks], acc[s][u], 0, 0, 0);
#pragma unroll
            for (int u = 0; u < 2; ++u) {
                int col = (w * 2 + u) * 16 + mrow;
                float bb = bo[l * 128 + col];
#pragma unroll
                for (int s = 0; s < 2; ++s)
#pragma unroll
                    for (int r = 0; r < 4; ++r)
                        xs[s * 2048 + (quad * 4 + r) * 128 + col] += acc[s][u][r] + bb;
            }
        }
        __syncthreads();
        ln256(xs, ln1s + l * 128, ln1b + l * 128);
        ln256(xs + 2048, ln1s + l * 128, ln1b + l * 128);
        // ---- xs -> xb16 (post-LN1, both seqs) ----
#pragma unroll
        for (int s = 0; s < 2; ++s) {
            const float* xp = xs + s * 2048 + crow * 128 + ccb;
            unsigned v[4];
#pragma unroll
            for (int j = 0; j < 4; ++j)
                v[j] = (unsigned)f2b(xp[2 * j]) | ((unsigned)f2b(xp[2 * j + 1]) << 16);
            *(uint4*)(xb16 + s * 2176 + crow * 136 + ccb) = make_uint4(v[0], v[1], v[2], v[3]);
        }
        __syncthreads();
        // ---- FF1 via MFMA: wave w does nt = 8w..8w+7, batched; relu -> hid16 ----
        {
            bf16x8 af[2][4];
#pragma unroll
            for (int s = 0; s < 2; ++s)
#pragma unroll
                for (int ks = 0; ks < 4; ++ks)
                    af[s][ks] = *(const bf16x8*)(xb16 + s * 2176 + mrow * 136 + ks * 32 + quad * 8);
            f32x4 acc[2][8];
#pragma unroll
            for (int s = 0; s < 2; ++s)
#pragma unroll
                for (int i = 0; i < 8; ++i) acc[s][i] = (f32x4){0.f, 0.f, 0.f, 0.f};
            const unsigned short* Ws = Wl + 65536;
#pragma unroll
            for (int ib = 0; ib < 4; ++ib) {
                bf16x8 wb[8];
#pragma unroll
                for (int u = 0; u < 2; ++u) {
                    int nt = w * 8 + ib * 2 + u;
#pragma unroll
                    for (int ks = 0; ks < 4; ++ks)
                        wb[u * 4 + ks] = *(const bf16x8*)(Ws + (size_t)((nt * 4 + ks) * 64 + lane) * 8);
                }
#pragma unroll
                for (int u = 0; u < 2; ++u)
#pragma unroll
                    for (int ks = 0; ks < 4; ++ks)
#pragma unroll
                        for (int s = 0; s < 2; ++s)
                            acc[s][ib * 2 + u] = __builtin_amdgcn_mfma_f32_16x16x32_bf16(af[s][ks], wb[u * 4 + ks], acc[s][ib * 2 + u], 0, 0, 0);
            }
#pragma unroll
            for (int i = 0; i < 8; ++i) {
                int col = (w * 8 + i) * 16 + mrow;
                float bb = bff1[l * 512 + col];
#pragma unroll
                for (int s = 0; s < 2; ++s)
#pragma unroll
                    for (int r = 0; r < 4; ++r) {
                        float v = fmaxf(acc[s][i][r] + bb, 0.f);
                        hid16[s * 8320 + (quad * 4 + r) * 520 + col] = f2b(v);
                    }
            }
        }
        __syncthreads();
        // ---- FF2 via MFMA: 2 nt x 16 ks per wave, 2 seqs ----
        {
            f32x4 acc[2][2];
#pragma unroll
            for (int s = 0; s < 2; ++s) { acc[s][0] = (f32x4){0,0,0,0}; acc[s][1] = (f32x4){0,0,0,0}; }
            const unsigned short* Ws = Wl + 131072;
            int nt0 = w * 2, nt1 = w * 2 + 1;
#pragma unroll
            for (int kb = 0; kb < 4; ++kb) {
                bf16x8 afb[2][4], w0[4], w1[4];
#pragma unroll
                for (int kk = 0; kk < 4; ++kk) {
                    int ks = kb * 4 + kk;
#pragma unroll
                    for (int s = 0; s < 2; ++s)
                        afb[s][kk] = *(const bf16x8*)(hid16 + s * 8320 + mrow * 520 + ks * 32 + quad * 8);
                    w0[kk] = *(const bf16x8*)(Ws + (size_t)((nt0 * 16 + ks) * 64 + lane) * 8);
                    w1[kk] = *(const bf16x8*)(Ws + (size_t)((nt1 * 16 + ks) * 64 + lane) * 8);
                }
#pragma unroll
                for (int kk = 0; kk < 4; ++kk)
#pragma unroll
                    for (int s = 0; s < 2; ++s) {
                        acc[s][0] = __builtin_amdgcn_mfma_f32_16x16x32_bf16(afb[s][kk], w0[kk], acc[s][0], 0, 0, 0);
                        acc[s][1] = __builtin_amdgcn_mfma_f32_16x16x32_bf16(afb[s][kk], w1[kk], acc[s][1], 0, 0, 0);
                    }
            }
            int col0 = nt0 * 16 + mrow, col1 = nt1 * 16 + mrow;
            float bb0 = bff2[l * 128 + col0], bb1 = bff2[l * 128 + col1];
#pragma unroll
            for (int s = 0; s < 2; ++s)
#pragma unroll
                for (int r = 0; r < 4; ++r) {
                    xs[s * 2048 + (quad * 4 + r) * 128 + col0] += acc[s][0][r] + bb0;
                    xs[s * 2048 + (quad * 4 + r) * 128 + col1] += acc[s][1][r] + bb1;
                }
        }
        __syncthreads();
        ln256(xs, ln2s + l * 128, ln2b + l * 128);
        ln256(xs + 2048, ln2s + l * 128, ln2b + l * 128);
    }
    for (int idx = tid; idx < 4096; idx += 256)
        out[(size_t)(2 * m + (idx >> 11)) * 2048 + (idx & 2047)] = xs[idx];
}

extern "C" void kernel_launch(void* const* d_in, const int* in_sizes, int n_in,
                              void* d_out, int out_size, void* d_ws, size_t ws_size,
                              hipStream_t stream) {
    (void)in_sizes; (void)n_in; (void)out_size; (void)ws_size;
    const int*   ego  = (const int*)d_in[0];
    const float* pos  = (const float*)d_in[1];
    const float* adj  = (const float*)d_in[2];
    const float* g1W  = (const float*)d_in[3];
    const float* g1as = (const float*)d_in[4];
    const float* g1ad = (const float*)d_in[5];
    const float* g1b  = (const float*)d_in[6];
    const float* gW   = (const float*)d_in[7];
    const float* gas  = (const float*)d_in[8];
    const float* gad  = (const float*)d_in[9];
    const float* gb   = (const float*)d_in[10];
    const float* Wqkv = (const float*)d_in[11];
    const float* bqkv = (const float*)d_in[12];
    const float* Wo   = (const float*)d_in[13];
    const float* bo   = (const float*)d_in[14];
    const float* l1s  = (const float*)d_in[15];
    const float* l1b  = (const float*)d_in[16];
    const float* l2s  = (const float*)d_in[17];
    const float* l2b  = (const float*)d_in[18];
    const float* Wff1 = (const float*)d_in[19];
    const float* bff1 = (const float*)d_in[20];
    const float* Wff2 = (const float*)d_in[21];
    const float* bff2 = (const float*)d_in[22];

    unsigned short* x0  = (unsigned short*)d_ws;       // 2,097,152 sh (4 MB)
    unsigned short* x1  = x0 + 2097152;                // 4 MB
    unsigned short* h16 = x1 + 2097152;                // 8,388,608 sh (16 MB)
    float* ssb = (float*)(h16 + 8388608);              // 65,536 f
    float* sdb = ssb + 65536;                          // 65,536 f
    float* mfl = sdb + 65536;                          // 16,384 f
    int*   cnt = (int*)(mfl + 16384);                  // 16,384 i
    int*   nbr = cnt + 16384;                          // 1,048,576 i
    unsigned short* Wb16 = (unsigned short*)(nbr + 1048576);  // 1,310,720 sh (~2.6 MB)
    unsigned short* Wg16 = Wb16 + 983040;              // GAT weight frags

    k_prep<<<640, 256, 0, stream>>>(Wqkv, Wo, Wff1, Wff2, gW, Wb16);
    k_init<<<64, 256, 0, stream>>>(ego, mfl, cnt);
    k_edges<<<256, 256, 0, stream>>>(adj, mfl, cnt, nbr);

    // GAT layer 1 (F=2), projection + ss/sd fused
    k_gat1<<<NROWS, 128, 0, stream>>>(pos, g1W, g1as, g1ad, h16, ssb, sdb);
    k_agg<<<NROWS, 128, 0, stream>>>(h16, ssb, sdb, cnt, nbr, mfl, g1b, x0);

    unsigned short* xin = x0; unsigned short* xout = x1;
    for (int L = 0; L < 5; ++L) {
        k_gat_h<<<1024, 256, 0, stream>>>(xin, Wg16 + (size_t)L * 65536,
                                          gas + L * 512, gad + L * 512, h16, ssb, sdb);
        k_agg<<<NROWS, 128, 0, stream>>>(h16, ssb, sdb, cnt, nbr, mfl, gb + L * 128, xout);
        unsigned short* tmp = xin; xin = xout; xout = tmp;
    }

    k_tf<<<512, 256, 0, stream>>>(xin, Wb16, bqkv, bo, l1s, l1b, l2s, l2b,
                                  bff1, bff2, (float*)d_out);
}

// Round 11
// 554.843 us; speedup vs baseline: 3.6596x; 1.2507x over previous
//
#include <hip/hip_runtime.h>
#include <hip/hip_bf16.h>

// Problem constants
#define TT 16
#define MM 1024
#define HDIM 128
#define NHEADS 4
#define NROWS (TT*MM)          // 16384
#define MAXDEG 64

typedef __bf16 bf16x8 __attribute__((ext_vector_type(8)));
typedef float f32x4 __attribute__((ext_vector_type(4)));

__device__ __forceinline__ unsigned short f2b(float x) {   // fp32 -> bf16 RNE
    unsigned u = __float_as_uint(x);
    u += 0x7fff + ((u >> 16) & 1);
    return (unsigned short)(u >> 16);
}
__device__ __forceinline__ float bu2f(unsigned short u) {
    return __uint_as_float(((unsigned)u) << 16);
}

// ---------------- mask + neighbor-list build ----------------
__global__ __launch_bounds__(256) void k_init(const int* __restrict__ ego,
                                              float* __restrict__ mfl,
                                              int* __restrict__ cnt) {
    int idx = blockIdx.x * 256 + threadIdx.x;   // < 16384
    int t = idx >> 10, i = idx & 1023;
    int b = i >> 8, n = i & 255;
    mfl[idx] = ego[b * (TT * 256) + t * 256 + n] ? 1.f : 0.f;
    cnt[idx] = 0;
}

// 1024 blocks: t(16) x jc(64); thread covers 4 i via float4; 16 j-rows/block.
__global__ __launch_bounds__(256) void k_edges(const float* __restrict__ adj,
                                               const float* __restrict__ mfl,
                                               int* __restrict__ cnt,
                                               int* __restrict__ nbr) {
    int bid = blockIdx.x;
    int t = bid >> 6, jc = bid & 63;
    int tid = threadIdx.x;
    int i0 = tid * 4;
    int rowb = t * MM;
    float mi[4];
#pragma unroll
    for (int r = 0; r < 4; ++r) mi[r] = mfl[rowb + i0 + r];
    __shared__ float ms[16];
    if (tid < 16) ms[tid] = mfl[rowb + jc * 16 + tid];
    __syncthreads();
    const float* at = adj + (size_t)t * MM * MM;
#pragma unroll 4
    for (int jj = 0; jj < 16; ++jj) {
        int j = jc * 16 + jj;
        float4 a = *(const float4*)(at + (size_t)j * MM + i0);
        float mj = ms[jj];
#pragma unroll
        for (int r = 0; r < 4; ++r) {
            int i = i0 + r;
            bool e;
            if (j == i) e = (mi[r] != 0.f);                       // self-loop
            else e = ((&a.x)[r] != 0.f) && (mj != 0.f) && (mi[r] != 0.f);
            if (e) {
                int row = rowb + i;
                int pos = atomicAdd(&cnt[row], 1);
                if (pos < MAXDEG) nbr[(size_t)row * MAXDEG + pos] = j;
            }
        }
    }
}

// ---------------- weight prep: fp32 -> bf16 MFMA B-fragment order ----------------
__global__ __launch_bounds__(256) void k_prep(const float* __restrict__ Wqkv,
                                              const float* __restrict__ Wo,
                                              const float* __restrict__ Wff1,
                                              const float* __restrict__ Wff2,
                                              const float* __restrict__ gW,
                                              unsigned short* __restrict__ Wb) {
    int o = blockIdx.x * 256 + threadIdx.x;     // frag-unit (8 elems) index, < 163840
    const float* src; int cs;
    if (o < 122880) {
        int l = o / 24576, r = o % 24576;
        if (r < 6144) {                 // QKV
            int nt = r >> 8, rem = r & 255, ks = rem >> 6, lane = rem & 63;
            int mt = nt >> 3, cc = nt & 7;
            int k = ks * 32 + ((lane >> 4) << 3), c = cc * 16 + (lane & 15);
            src = Wqkv + ((size_t)(l * 3 + mt) * 128 + k) * 128 + c; cs = 128;
        } else if (r < 8192) {          // Wo
            int u = r - 6144, nt = u >> 8, rem = u & 255, ks = rem >> 6, lane = rem & 63;
            int k = ks * 32 + ((lane >> 4) << 3), c = nt * 16 + (lane & 15);
            src = Wo + (size_t)l * 16384 + (size_t)k * 128 + c; cs = 128;
        } else if (r < 16384) {         // FF1
            int u = r - 8192, nt = u >> 8, rem = u & 255, ks = rem >> 6, lane = rem & 63;
            int k = ks * 32 + ((lane >> 4) << 3), c = nt * 16 + (lane & 15);
            src = Wff1 + (size_t)l * 65536 + (size_t)k * 512 + c; cs = 512;
        } else {                        // FF2
            int u = r - 16384, nt = u >> 10, rem = u & 1023, ks = rem >> 6, lane = rem & 63;
            int k = ks * 32 + ((lane >> 4) << 3), c = nt * 16 + (lane & 15);
            src = Wff2 + (size_t)l * 65536 + (size_t)k * 128 + c; cs = 128;
        }
    } else {                            // GAT gW
        int u = o - 122880;
        int l = u >> 13, rr = u & 8191;
        int nt = rr >> 8, rem = rr & 255, ks = rem >> 6, lane = rem & 63;
        int k = ks * 32 + ((lane >> 4) << 3), c = nt * 16 + (lane & 15);
        src = gW + (size_t)l * 65536 + (size_t)k * 512 + c; cs = 512;
    }
    unsigned v[4];
#pragma unroll
    for (int j = 0; j < 4; ++j)
        v[j] = (unsigned)f2b(src[(2 * j) * (size_t)cs]) |
               ((unsigned)f2b(src[(2 * j + 1) * (size_t)cs]) << 16);
    *(uint4*)(Wb + (size_t)o * 8) = make_uint4(v[0], v[1], v[2], v[3]);
}

// ---------------- GAT layer 1: projection (F=2) + fused ss/sd; h -> bf16 ----------------
__global__ __launch_bounds__(128) void k_gat1(const float* __restrict__ x,
                                              const float* __restrict__ W,
                                              const float* __restrict__ asrc,
                                              const float* __restrict__ adst,
                                              unsigned short* __restrict__ h16,
                                              float* __restrict__ ss,
                                              float* __restrict__ sd) {
    int bid = blockIdx.x;
    int row = ((bid & 7) << 11) + (bid >> 3);   // XCD-locality swizzle
    int tid = threadIdx.x;
    float x0 = x[row * 2], x1 = x[row * 2 + 1];
    float s4[4], d4[4];
#pragma unroll
    for (int hh = 0; hh < 4; ++hh) {
        int o = hh * 128 + tid;
        float v = x0 * W[o] + x1 * W[512 + o];
        h16[(size_t)row * 512 + o] = f2b(v);
        s4[hh] = v * asrc[o];
        d4[hh] = v * adst[o];
    }
#pragma unroll
    for (int hh = 0; hh < 4; ++hh)
        for (int off = 32; off; off >>= 1) {
            s4[hh] += __shfl_down(s4[hh], off, 64);
            d4[hh] += __shfl_down(d4[hh], off, 64);
        }
    __shared__ float red[2][2][4];
    if ((tid & 63) == 0) {
        int w = tid >> 6;
#pragma unroll
        for (int hh = 0; hh < 4; ++hh) { red[w][0][hh] = s4[hh]; red[w][1][hh] = d4[hh]; }
    }
    __syncthreads();
    if (tid < 4) ss[row * 4 + tid] = red[0][0][tid] + red[1][0][tid];
    else if (tid < 8) sd[row * 4 + tid - 4] = red[0][1][tid - 4] + red[1][1][tid - 4];
}

// ---------------- GAT layers 2-6: MFMA projection + fused ss/sd ----------------
__global__ __launch_bounds__(256) void k_gat_h(const unsigned short* __restrict__ x16,
                                               const unsigned short* __restrict__ Wg,
                                               const float* __restrict__ asrc,
                                               const float* __restrict__ adst,
                                               unsigned short* __restrict__ h16,
                                               float* __restrict__ ss,
                                               float* __restrict__ sd) {
    __shared__ __align__(16) unsigned short xb[16 * 136];
    int bid = blockIdx.x;
    int row0 = (((bid & 7) << 7) + (bid >> 3)) * 16;   // band swizzle, XCD mapping
    int tid = threadIdx.x;
    {
        int rr = tid >> 4, cc = (tid & 15) * 8;
        *(uint4*)(xb + rr * 136 + cc) = *(const uint4*)(x16 + (size_t)(row0 + rr) * 128 + cc);
    }
    __syncthreads();
    const int lane = tid & 63, w = tid >> 6;
    const int mrow = lane & 15, quad = lane >> 4;
    bf16x8 af[4];
#pragma unroll
    for (int ks = 0; ks < 4; ++ks)
        af[ks] = *(const bf16x8*)(xb + mrow * 136 + ks * 32 + quad * 8);
    f32x4 acc[8];
#pragma unroll
    for (int i = 0; i < 8; ++i) acc[i] = (f32x4){0.f, 0.f, 0.f, 0.f};
#pragma unroll
    for (int ib = 0; ib < 4; ++ib) {   // batches of 2 nt x 4 ks -> 8 loads in flight
        bf16x8 wb[8];
#pragma unroll
        for (int u = 0; u < 2; ++u) {
            int nt = w * 8 + ib * 2 + u;
#pragma unroll
            for (int ks = 0; ks < 4; ++ks)
                wb[u * 4 + ks] = *(const bf16x8*)(Wg + (size_t)((nt * 4 + ks) * 64 + lane) * 8);
        }
#pragma unroll
        for (int u = 0; u < 2; ++u)
#pragma unroll
            for (int ks = 0; ks < 4; ++ks)
                acc[ib * 2 + u] = __builtin_amdgcn_mfma_f32_16x16x32_bf16(af[ks], wb[u * 4 + ks], acc[ib * 2 + u], 0, 0, 0);
    }
    float ps[4] = {0, 0, 0, 0}, pd[4] = {0, 0, 0, 0};
#pragma unroll
    for (int i = 0; i < 8; ++i) {
        int nt = w * 8 + i, col = nt * 16 + mrow;
        float as_ = asrc[col], ad_ = adst[col];
#pragma unroll
        for (int r = 0; r < 4; ++r) {
            float v = acc[i][r];
            h16[(size_t)(row0 + quad * 4 + r) * 512 + col] = f2b(v);
            ps[r] += v * as_; pd[r] += v * ad_;
        }
    }
#pragma unroll
    for (int off = 1; off < 16; off <<= 1)
#pragma unroll
        for (int r = 0; r < 4; ++r) {
            ps[r] += __shfl_xor(ps[r], off, 64);
            pd[r] += __shfl_xor(pd[r], off, 64);
        }
    if (mrow == 0) {
#pragma unroll
        for (int r = 0; r < 4; ++r) {
            int row = row0 + quad * 4 + r;
            ss[row * 4 + w] = ps[r];
            sd[row * 4 + w] = pd[r];
        }
    }
}

// ---------------- GAT aggregation: vectorized bf16 gather + parallel softmax -------------
__global__ __launch_bounds__(128) void k_agg(const unsigned short* __restrict__ h16,
                                             const float* __restrict__ ss,
                                             const float* __restrict__ sd,
                                             const int* __restrict__ cnt,
                                             const int* __restrict__ nbr,
                                             const float* __restrict__ mfl,
                                             const float* __restrict__ bias,
                                             unsigned short* __restrict__ xo16) {
    int bid = blockIdx.x;
    int row = ((bid & 7) << 11) + (bid >> 3);   // same-t rows colocate per XCD
    int tid = threadIdx.x;
    int t = row >> 10;
    if (mfl[row] == 0.f) { xo16[(size_t)row * 128 + tid] = 0; return; }
    int c = cnt[row]; if (c > MAXDEG) c = MAXDEG;
    __shared__ int nb[MAXDEG];
    __shared__ float al[MAXDEG][4];
    __shared__ __align__(16) float part[512];
    if (tid < c) nb[tid] = nbr[(size_t)row * MAXDEG + tid];
    __syncthreads();
    for (int idx = tid; idx < c * 4; idx += 128) {
        int n = idx >> 2, hh = idx & 3, j = nb[n];
        float lg = sd[row * 4 + hh] + ss[(t * MM + j) * 4 + hh];
        al[n][hh] = lg > 0.f ? lg : 0.2f * lg;   // leaky_relu 0.2
    }
    __syncthreads();
    // parallel segment softmax: 32 lanes per head
    {
        int hh = tid >> 5, n0 = tid & 31;
        float v1 = (n0 < c) ? al[n0][hh] : -1e30f;
        float v2 = (n0 + 32 < c) ? al[n0 + 32][hh] : -1e30f;
        float mx = fmaxf(v1, v2);
#pragma unroll
        for (int off = 16; off; off >>= 1) mx = fmaxf(mx, __shfl_xor(mx, off, 32));
        float e1 = (n0 < c) ? __expf(v1 - mx) : 0.f;
        float e2 = (n0 + 32 < c) ? __expf(v2 - mx) : 0.f;
        float s = e1 + e2;
#pragma unroll
        for (int off = 16; off; off >>= 1) s += __shfl_xor(s, off, 32);
        float inv = 1.f / s;
        if (n0 < c) al[n0][hh] = e1 * inv;
        if (n0 + 32 < c) al[n0 + 32][hh] = e2 * inv;
    }
    __syncthreads();
    // gather: thread owns 4 consecutive cols (one uint2 = 4 bf16 per neighbor)
    float a0 = 0.f, a1 = 0.f, a2 = 0.f, a3 = 0.f;
    int hh2 = tid >> 5;
    const unsigned short* hbase = h16 + (size_t)t * MM * 512 + tid * 4;
    for (int n = 0; n < c; ++n) {
        int j = nb[n];
        uint2 v = *(const uint2*)(hbase + (size_t)j * 512);
        float w = al[n][hh2];
        a0 += w * bu2f((unsigned short)(v.x & 0xffff));
        a1 += w * bu2f((unsigned short)(v.x >> 16));
        a2 += w * bu2f((unsigned short)(v.y & 0xffff));
        a3 += w * bu2f((unsigned short)(v.y >> 16));
    }
    *(float4*)(part + tid * 4) = make_float4(a0, a1, a2, a3);
    __syncthreads();
    float v = 0.25f * (part[tid] + part[128 + tid] + part[256 + tid] + part[384 + tid]) + bias[tid];
    xo16[(size_t)row * 128 + tid] = f2b(fmaxf(v, 0.f));
}

// ---------------- in-place LayerNorm, 16 rows x 128, 256 threads ----------------
__device__ __forceinline__ void ln256(float* xs, const float* s, const float* b) {
    int tid = threadIdx.x, row = tid >> 4, lane = tid & 15;
    float* xr = xs + row * 128;
    float sum = 0.f;
#pragma unroll
    for (int k2 = 0; k2 < 8; ++k2) sum += xr[lane + 16 * k2];
#pragma unroll
    for (int off = 8; off; off >>= 1) sum += __shfl_xor(sum, off, 16);
    float mean = sum * (1.f / 128.f);
    float vs = 0.f;
#pragma unroll
    for (int k2 = 0; k2 < 8; ++k2) { float d = xr[lane + 16 * k2] - mean; vs += d * d; }
#pragma unroll
    for (int off = 8; off; off >>= 1) vs += __shfl_xor(vs, off, 16);
    float rstd = rsqrtf(vs * (1.f / 128.f) + 1e-5f);
#pragma unroll
    for (int k2 = 0; k2 < 8; ++k2) {
        int d = lane + 16 * k2;
        float v = (xr[d] - mean) * rstd;
        xr[d] = v * s[d] + b[d];
    }
    __syncthreads();
}

// ---------------- 5-layer transformer: 2 sequences/block, MFMA bf16, batched loads -------
// LDS = 4096(xs) + 4224(Qf) + 4224(Kf) + 2048(sb) + 2176(Vf16) + 2176(xb16) = 18944 fl
// = 75776 B -> 2 blocks/CU; grid 512 = ONE pass. Each weight load feeds 2 MFMAs.
__global__ __launch_bounds__(256, 2) void k_tf(const unsigned short* __restrict__ xg,
        const unsigned short* __restrict__ Wb,
        const float* __restrict__ bqkv, const float* __restrict__ bo,
        const float* __restrict__ ln1s, const float* __restrict__ ln1b,
        const float* __restrict__ ln2s, const float* __restrict__ ln2b,
        const float* __restrict__ bff1, const float* __restrict__ bff2,
        float* __restrict__ out) {
    __shared__ __align__(16) float smem[18944];
    float* xs = smem;                  // [2][16][128] residual fp32
    float* Qf = smem + 4096;           // [2][16][132] fp32
    float* Kf = smem + 8320;           // [2][16][132] fp32
    float* sb = smem + 12544;          // [2][16tk][64] transposed scores
    unsigned short* Vf16  = (unsigned short*)(smem + 14592); // [2][16][136] bf16
    unsigned short* xb16  = (unsigned short*)(smem + 16768); // [2][16][136] bf16 A-operand
    unsigned short* hid16 = (unsigned short*)(smem + 4096);  // [2][16][520] bf16, overlays Qf+Kf
    const int m = blockIdx.x, tid = threadIdx.x;
    const int lane = tid & 63, w = tid >> 6;
    const int mrow = lane & 15, quad = lane >> 4;

    // load + sinusoidal PE (2 seqs)
    for (int idx = tid; idx < 4096; idx += 256) {
        int seq = idx >> 11, t = (idx >> 7) & 15, d = idx & 127, jj = d >> 1;
        float arg = (float)t * expf(-(float)(2 * jj) * (9.210340371976184f / 128.f));
        float pe = (d & 1) ? cosf(arg) : sinf(arg);
        xs[idx] = bu2f(xg[(size_t)t * (MM * HDIM) + (size_t)(2 * m + seq) * HDIM + d]) + pe;
    }
    __syncthreads();

    const int crow = tid >> 4, ccb = (tid & 15) * 8;   // xs->xb16 conversion slots
    for (int l = 0; l < 5; ++l) {
        const unsigned short* Wl = Wb + (size_t)l * 196608;
        // ---- xs -> xb16 (both seqs) ----
#pragma unroll
        for (int s = 0; s < 2; ++s) {
            const float* xp = xs + s * 2048 + crow * 128 + ccb;
            unsigned v[4];
#pragma unroll
            for (int j = 0; j < 4; ++j)
                v[j] = (unsigned)f2b(xp[2 * j]) | ((unsigned)f2b(xp[2 * j + 1]) << 16);
            *(uint4*)(xb16 + s * 2176 + crow * 136 + ccb) = make_uint4(v[0], v[1], v[2], v[3]);
        }
        __syncthreads();
        // ---- QKV via MFMA: wave w does nt = 6w..6w+5, 2 seqs per weight load ----
        {
            bf16x8 af[2][4];
#pragma unroll
            for (int s = 0; s < 2; ++s)
#pragma unroll
                for (int ks = 0; ks < 4; ++ks)
                    af[s][ks] = *(const bf16x8*)(xb16 + s * 2176 + mrow * 136 + ks * 32 + quad * 8);
            f32x4 acc[2][6];
#pragma unroll
            for (int s = 0; s < 2; ++s)
#pragma unroll
                for (int i = 0; i < 6; ++i) acc[s][i] = (f32x4){0.f, 0.f, 0.f, 0.f};
#pragma unroll
            for (int ib = 0; ib < 3; ++ib) {
                bf16x8 wb[8];
#pragma unroll
                for (int u = 0; u < 2; ++u) {
                    int nt = w * 6 + ib * 2 + u;
                    const unsigned short* bp = Wl + (size_t)(nt * 4) * 512 + lane * 8;
#pragma unroll
                    for (int ks = 0; ks < 4; ++ks)
                        wb[u * 4 + ks] = *(const bf16x8*)(bp + ks * 512);
                }
#pragma unroll
                for (int u = 0; u < 2; ++u)
#pragma unroll
                    for (int ks = 0; ks < 4; ++ks)
#pragma unroll
                        for (int s = 0; s < 2; ++s)
                            acc[s][ib * 2 + u] = __builtin_amdgcn_mfma_f32_16x16x32_bf16(af[s][ks], wb[u * 4 + ks], acc[s][ib * 2 + u], 0, 0, 0);
            }
#pragma unroll
            for (int i = 0; i < 6; ++i) {
                int nt = w * 6 + i, mt = nt >> 3, cc = nt & 7;
                int col = cc * 16 + mrow;
                float bb = bqkv[l * 384 + mt * 128 + col];
#pragma unroll
                for (int s = 0; s < 2; ++s) {
                    if (mt == 2) {
#pragma unroll
                        for (int r = 0; r < 4; ++r)
                            Vf16[s * 2176 + (quad * 4 + r) * 136 + col] = f2b(acc[s][i][r] + bb);
                    } else {
                        float* dst = ((mt == 0) ? Qf : Kf) + s * 2112;
#pragma unroll
                        for (int r = 0; r < 4; ++r)
                            dst[(quad * 4 + r) * 132 + col] = acc[s][i][r] + bb;
                    }
                }
            }
        }
        __syncthreads();
        // ---- scores (fp32 VALU), both seqs ----
#pragma unroll
        for (int s = 0; s < 2; ++s) {
            int hh = tid >> 6, tq = (tid >> 2) & 15, tk0 = (tid & 3) * 4;
            const float* qp = Qf + s * 2112 + tq * 132 + hh * 32;
            float a[4] = {0.f, 0.f, 0.f, 0.f};
#pragma unroll
            for (int d = 0; d < 8; ++d) {
                float4 q4 = *(const float4*)(qp + 4 * d);
#pragma unroll
                for (int j = 0; j < 4; ++j) {
                    float4 k4 = *(const float4*)(Kf + s * 2112 + (tk0 + j) * 132 + hh * 32 + 4 * d);
                    a[j] += q4.x * k4.x + q4.y * k4.y + q4.z * k4.z + q4.w * k4.w;
                }
            }
#pragma unroll
            for (int j = 0; j < 4; ++j)
                sb[s * 1024 + (tk0 + j) * 64 + hh * 16 + tq] = a[j] * 0.17677669529663687f;
        }
        __syncthreads();
        if (tid < 128) {   // softmax per (seq,hh,tq) column
            int s = tid >> 6, col = tid & 63;
            float* sp = sb + s * 1024;
            float mx = -1e30f;
#pragma unroll
            for (int u = 0; u < 16; ++u) mx = fmaxf(mx, sp[u * 64 + col]);
            float sm = 0.f;
#pragma unroll
            for (int u = 0; u < 16; ++u) { float e = __expf(sp[u * 64 + col] - mx); sp[u * 64 + col] = e; sm += e; }
            float inv = 1.f / sm;
#pragma unroll
            for (int u = 0; u < 16; ++u) sp[u * 64 + col] *= inv;
        }
        __syncthreads();
        // ---- O = P @ V (fp32, bf16 V) -> xb16, both seqs ----
#pragma unroll
        for (int s = 0; s < 2; ++s) {
            int o = tid & 127, r0p = (tid >> 7) * 8, hh = o >> 5;
            float accp[8] = {0, 0, 0, 0, 0, 0, 0, 0};
            for (int u = 0; u < 16; ++u) {
                float vv = bu2f(Vf16[s * 2176 + u * 136 + o]);
                const float* pp = sb + s * 1024 + u * 64 + hh * 16 + r0p;
#pragma unroll
                for (int r = 0; r < 8; ++r) accp[r] += pp[r] * vv;
            }
#pragma unroll
            for (int r = 0; r < 8; ++r)
                xb16[s * 2176 + (r0p + r) * 136 + o] = f2b(accp[r]);
        }
        __syncthreads();
        // ---- Wo via MFMA: wave w does nt = 2w, 2w+1 ----
        {
            bf16x8 af[2][4];
#pragma unroll
            for (int s = 0; s < 2; ++s)
#pragma unroll
                for (int ks = 0; ks < 4; ++ks)
                    af[s][ks] = *(const bf16x8*)(xb16 + s * 2176 + mrow * 136 + ks * 32 + quad * 8);
            const unsigned short* Ws = Wl + 49152;
            bf16x8 wb[8];
#pragma unroll
            for (int u = 0; u < 2; ++u) {
                int nt = w * 2 + u;
#pragma unroll
                for (int ks = 0; ks < 4; ++ks)
                    wb[u * 4 + ks] = *(const bf16x8*)(Ws + (size_t)((nt * 4 + ks) * 64 + lane) * 8);
            }
            f32x4 acc[2][2];
#pragma unroll
            for (int s = 0; s < 2; ++s) { acc[s][0] = (f32x4){0,0,0,0}; acc[s][1] = (f32x4){0,0,0,0}; }
#pragma unroll
            for (int u = 0; u < 2; ++u)
#pragma unroll
                for (int ks = 0; ks < 4; ++ks)
#pragma unroll
                    for (int s = 0; s < 2; ++s)
                        acc[s][u] = __builtin_amdgcn_mfma_f32_16x16x32_bf16(af[s][ks], wb[u * 4 + ks], acc[s][u], 0, 0, 0);
#pragma unroll
            for (int u = 0; u < 2; ++u) {
                int col = (w * 2 + u) * 16 + mrow;
                float bb = bo[l * 128 + col];
#pragma unroll
                for (int s = 0; s < 2; ++s)
#pragma unroll
                    for (int r = 0; r < 4; ++r)
                        xs[s * 2048 + (quad * 4 + r) * 128 + col] += acc[s][u][r] + bb;
            }
        }
        __syncthreads();
        ln256(xs, ln1s + l * 128, ln1b + l * 128);
        ln256(xs + 2048, ln1s + l * 128, ln1b + l * 128);
        // ---- xs -> xb16 (post-LN1, both seqs) ----
#pragma unroll
        for (int s = 0; s < 2; ++s) {
            const float* xp = xs + s * 2048 + crow * 128 + ccb;
            unsigned v[4];
#pragma unroll
            for (int j = 0; j < 4; ++j)
                v[j] = (unsigned)f2b(xp[2 * j]) | ((unsigned)f2b(xp[2 * j + 1]) << 16);
            *(uint4*)(xb16 + s * 2176 + crow * 136 + ccb) = make_uint4(v[0], v[1], v[2], v[3]);
        }
        __syncthreads();
        // ---- FF1 via MFMA: wave w does nt = 8w..8w+7, batched; relu -> hid16 ----
        {
            bf16x8 af[2][4];
#pragma unroll
            for (int s = 0; s < 2; ++s)
#pragma unroll
                for (int ks = 0; ks < 4; ++ks)
                    af[s][ks] = *(const bf16x8*)(xb16 + s * 2176 + mrow * 136 + ks * 32 + quad * 8);
            f32x4 acc[2][8];
#pragma unroll
            for (int s = 0; s < 2; ++s)
#pragma unroll
                for (int i = 0; i < 8; ++i) acc[s][i] = (f32x4){0.f, 0.f, 0.f, 0.f};
            const unsigned short* Ws = Wl + 65536;
#pragma unroll
            for (int ib = 0; ib < 4; ++ib) {
                bf16x8 wb[8];
#pragma unroll
                for (int u = 0; u < 2; ++u) {
                    int nt = w * 8 + ib * 2 + u;
#pragma unroll
                    for (int ks = 0; ks < 4; ++ks)
                        wb[u * 4 + ks] = *(const bf16x8*)(Ws + (size_t)((nt * 4 + ks) * 64 + lane) * 8);
                }
#pragma unroll
                for (int u = 0; u < 2; ++u)
#pragma unroll
                    for (int ks = 0; ks < 4; ++ks)
#pragma unroll
                        for (int s = 0; s < 2; ++s)
                            acc[s][ib * 2 + u] = __builtin_amdgcn_mfma_f32_16x16x32_bf16(af[s][ks], wb[u * 4 + ks], acc[s][ib * 2 + u], 0, 0, 0);
            }
#pragma unroll
            for (int i = 0; i < 8; ++i) {
                int col = (w * 8 + i) * 16 + mrow;
                float bb = bff1[l * 512 + col];
#pragma unroll
                for (int s = 0; s < 2; ++s)
#pragma unroll
                    for (int r = 0; r < 4; ++r) {
                        float v = fmaxf(acc[s][i][r] + bb, 0.f);
                        hid16[s * 8320 + (quad * 4 + r) * 520 + col] = f2b(v);
                    }
            }
        }
        __syncthreads();
        // ---- FF2 via MFMA: 2 nt x 16 ks per wave, 2 seqs ----
        {
            f32x4 acc[2][2];
#pragma unroll
            for (int s = 0; s < 2; ++s) { acc[s][0] = (f32x4){0,0,0,0}; acc[s][1] = (f32x4){0,0,0,0}; }
            const unsigned short* Ws = Wl + 131072;
            int nt0 = w * 2, nt1 = w * 2 + 1;
#pragma unroll
            for (int kb = 0; kb < 4; ++kb) {
                bf16x8 afb[2][4], w0[4], w1[4];
#pragma unroll
                for (int kk = 0; kk < 4; ++kk) {
                    int ks = kb * 4 + kk;
#pragma unroll
                    for (int s = 0; s < 2; ++s)
                        afb[s][kk] = *(const bf16x8*)(hid16 + s * 8320 + mrow * 520 + ks * 32 + quad * 8);
                    w0[kk] = *(const bf16x8*)(Ws + (size_t)((nt0 * 16 + ks) * 64 + lane) * 8);
                    w1[kk] = *(const bf16x8*)(Ws + (size_t)((nt1 * 16 + ks) * 64 + lane) * 8);
                }
#pragma unroll
                for (int kk = 0; kk < 4; ++kk)
#pragma unroll
                    for (int s = 0; s < 2; ++s) {
                        acc[s][0] = __builtin_amdgcn_mfma_f32_16x16x32_bf16(afb[s][kk], w0[kk], acc[s][0], 0, 0, 0);
                        acc[s][1] = __builtin_amdgcn_mfma_f32_16x16x32_bf16(afb[s][kk], w1[kk], acc[s][1], 0, 0, 0);
                    }
            }
            int col0 = nt0 * 16 + mrow, col1 = nt1 * 16 + mrow;
            float bb0 = bff2[l * 128 + col0], bb1 = bff2[l * 128 + col1];
#pragma unroll
            for (int s = 0; s < 2; ++s)
#pragma unroll
                for (int r = 0; r < 4; ++r) {
                    xs[s * 2048 + (quad * 4 + r) * 128 + col0] += acc[s][0][r] + bb0;
                    xs[s * 2048 + (quad * 4 + r) * 128 + col1] += acc[s][1][r] + bb1;
                }
        }
        __syncthreads();
        ln256(xs, ln2s + l * 128, ln2b + l * 128);
        ln256(xs + 2048, ln2s + l * 128, ln2b + l * 128);
    }
    for (int idx = tid; idx < 4096; idx += 256)
        out[(size_t)(2 * m + (idx >> 11)) * 2048 + (idx & 2047)] = xs[idx];
}

extern "C" void kernel_launch(void* const* d_in, const int* in_sizes, int n_in,
                              void* d_out, int out_size, void* d_ws, size_t ws_size,
                              hipStream_t stream) {
    (void)in_sizes; (void)n_in; (void)out_size; (void)ws_size;
    const int*   ego  = (const int*)d_in[0];
    const float* pos  = (const float*)d_in[1];
    const float* adj  = (const float*)d_in[2];
    const float* g1W  = (const float*)d_in[3];
    const float* g1as = (const float*)d_in[4];
    const float* g1ad = (const float*)d_in[5];
    const float* g1b  = (const float*)d_in[6];
    const float* gW   = (const float*)d_in[7];
    const float* gas  = (const float*)d_in[8];
    const float* gad  = (const float*)d_in[9];
    const float* gb   = (const float*)d_in[10];
    const float* Wqkv = (const float*)d_in[11];
    const float* bqkv = (const float*)d_in[12];
    const float* Wo   = (const float*)d_in[13];
    const float* bo   = (const float*)d_in[14];
    const float* l1s  = (const float*)d_in[15];
    const float* l1b  = (const float*)d_in[16];
    const float* l2s  = (const float*)d_in[17];
    const float* l2b  = (const float*)d_in[18];
    const float* Wff1 = (const float*)d_in[19];
    const float* bff1 = (const float*)d_in[20];
    const float* Wff2 = (const float*)d_in[21];
    const float* bff2 = (const float*)d_in[22];

    unsigned short* x0  = (unsigned short*)d_ws;       // 2,097,152 sh (4 MB)
    unsigned short* x1  = x0 + 2097152;                // 4 MB
    unsigned short* h16 = x1 + 2097152;                // 8,388,608 sh (16 MB)
    float* ssb = (float*)(h16 + 8388608);              // 65,536 f
    float* sdb = ssb + 65536;                          // 65,536 f
    float* mfl = sdb + 65536;                          // 16,384 f
    int*   cnt = (int*)(mfl + 16384);                  // 16,384 i
    int*   nbr = cnt + 16384;                          // 1,048,576 i
    unsigned short* Wb16 = (unsigned short*)(nbr + 1048576);  // 1,310,720 sh (~2.6 MB)
    unsigned short* Wg16 = Wb16 + 983040;              // GAT weight frags

    k_prep<<<640, 256, 0, stream>>>(Wqkv, Wo, Wff1, Wff2, gW, Wb16);
    k_init<<<64, 256, 0, stream>>>(ego, mfl, cnt);
    k_edges<<<1024, 256, 0, stream>>>(adj, mfl, cnt, nbr);

    // GAT layer 1 (F=2), projection + ss/sd fused
    k_gat1<<<NROWS, 128, 0, stream>>>(pos, g1W, g1as, g1ad, h16, ssb, sdb);
    k_agg<<<NROWS, 128, 0, stream>>>(h16, ssb, sdb, cnt, nbr, mfl, g1b, x0);

    unsigned short* xin = x0; unsigned short* xout = x1;
    for (int L = 0; L < 5; ++L) {
        k_gat_h<<<1024, 256, 0, stream>>>(xin, Wg16 + (size_t)L * 65536,
                                          gas + L * 512, gad + L * 512, h16, ssb, sdb);
        k_agg<<<NROWS, 128, 0, stream>>>(h16, ssb, sdb, cnt, nbr, mfl, gb + L * 128, xout);
        unsigned short* tmp = xin; xin = xout; xout = tmp;
    }

    k_tf<<<512, 256, 0, stream>>>(xin, Wb16, bqkv, bo, l1s, l1b, l2s, l2b,
                                  bff1, bff2, (float*)d_out);
}